// Round 15
// baseline (132.781 us; speedup 1.0000x reference)
//
#include <hip/hip_runtime.h>
#include <hip/hip_bf16.h>
#include <hip/hip_fp16.h>

typedef unsigned short u16;
typedef _Float16 f16x8 __attribute__((ext_vector_type(8)));
typedef u16 u16x8 __attribute__((ext_vector_type(8)));
typedef u16 u16x4 __attribute__((ext_vector_type(4)));
typedef float f32x4 __attribute__((ext_vector_type(4)));

__device__ __forceinline__ u16 f2h(float f){
  __half h = __float2half(f);
  return *(u16*)&h;
}

// async 16B global -> LDS (dest = wave-uniform base + lane*16; src per-lane)
__device__ __forceinline__ void cp16_async(const u16* g, u16* l){
  __builtin_amdgcn_global_load_lds(
      (const __attribute__((address_space(1))) unsigned int*)g,
      (__attribute__((address_space(3))) unsigned int*)l,
      16, 0, 0);
}

// ---------------------------------------------------------------------------
// Weight prep (unchanged, verified): W f32 [co][ci][3][3] ->
// Wt fp16 frag-linear  Wt[((s*4+n)*64 + lane)*8 + j],  s=tap*2+(ci/32)
// ---------------------------------------------------------------------------
__device__ __forceinline__ void prep_w_body(const float* W, u16* Wt, int i){
  if (i >= 36864) return;
  int co = i / 576, rem = i % 576, ci = rem / 9, tap = rem % 9;
  int n = co >> 4, lr = co & 15, kk = ci >> 5, lg = (ci >> 3) & 3, j = ci & 7;
  int s = tap*2 + kk;
  Wt[(((s*4 + n)*64) + lg*16 + lr)*8 + j] = f2h(W[i]);
}

__global__ __launch_bounds__(256) void prep_w3(
    const float* __restrict__ Wq, const float* __restrict__ Wk,
    const float* __restrict__ Wv, u16* __restrict__ Wt)
{
  int which = blockIdx.y;
  const float* W = (which == 0) ? Wq : (which == 1) ? Wk : Wv;
  prep_w_body(W, Wt + which*36864, blockIdx.x * 256 + threadIdx.x);
}

__global__ __launch_bounds__(256) void prep_w(
    const float* __restrict__ W, u16* __restrict__ Wt)
{
  prep_w_body(W, Wt, blockIdx.x * 256 + threadIdx.x);
}

// ---------------------------------------------------------------------------
// Conv v13: producer-consumer wave specialization. 512 thr, 1 block/CU.
// Waves 0-3 compute frame f (R12 K-loop + R10 epilogue, bit-identical);
// waves 4-7 load+cvt frame f+1 into regs (asm-pinned) and pack into the
// other xT buffer between the epilogue barriers. F frames per block.
// ---------------------------------------------------------------------------
template<bool IN_F32, bool OUT_PROJ, int F>
__global__ __launch_bounds__(512, 2) void conv_pipe(
    const void* __restrict__ x0, const void* __restrict__ x1,
    const void* __restrict__ x2, const u16* __restrict__ Wt_base,
    int wt_stride, const float* __restrict__ b0,
    const float* __restrict__ b1, const float* __restrict__ b2,
    void* __restrict__ d0, void* __restrict__ d1, void* __restrict__ d2)
{
  __shared__ __align__(16) u16 xT0[324*64];
  __shared__ __align__(16) u16 xT1[324*64];
  const int tid = threadIdx.x;
  const int w = tid >> 6, lane = tid & 63, lr = lane & 15, lg = lane >> 4;
  const bool stagew = (w >= 4);
  const int sp = tid & 255;
  const int spy = sp >> 4, spx = sp & 15;
  const int spp = (spy + 1)*18 + spx + 1;
  const int gf0 = blockIdx.x * F;
  const int pyb = w * 4;                       // compute waves: 4 px-rows

  u16x8 pk[8];

  // stage: load 64 elems + cvt into pk[8]; asm keeps values materialized
  #define LOADCVT(gf) do {                                                  \
    int wh_ = (gf) >> 9, fr_ = (gf) & 511;                                  \
    const void* xs_ = (wh_==0)?x0:(wh_==1)?x1:x2;                           \
    if (IN_F32){                                                            \
      const float* s_ = (const float*)xs_ + (size_t)fr_*16384;              \
      float xv_[64];                                                        \
      _Pragma("unroll") for (int c=0;c<64;++c) xv_[c] = s_[c*256 + sp];     \
      _Pragma("unroll") for (int cb=0;cb<8;++cb){                           \
        u16x8 t_;                                                           \
        _Pragma("unroll") for (int j=0;j<8;++j) t_[j] = f2h(xv_[cb*8+j]);   \
        pk[cb] = t_;                                                        \
      }                                                                     \
    } else {                                                                \
      const u16* s_ = (const u16*)xs_ + (size_t)fr_*16384;                  \
      _Pragma("unroll") for (int cb=0;cb<8;++cb){                           \
        u16x8 t_;                                                           \
        _Pragma("unroll") for (int j=0;j<8;++j) t_[j] = s_[(cb*8+j)*256+sp];\
        pk[cb] = t_;                                                        \
      }                                                                     \
    }                                                                       \
    _Pragma("unroll") for (int cb=0;cb<8;++cb){                             \
      unsigned* pw_ = (unsigned*)&pk[cb];                                   \
      asm volatile("" :: "v"(pw_[0]), "v"(pw_[1]), "v"(pw_[2]), "v"(pw_[3]));\
    }                                                                       \
  } while(0)

  #define PACKW(buf) do {                                                   \
    _Pragma("unroll") for (int cb=0;cb<8;++cb){                             \
      unsigned off_ = (unsigned)(spp*128)                                   \
                      + ((((unsigned)cb + (unsigned)spp) & 7u) << 4);       \
      *(u16x8*)((char*)(buf) + off_) = pk[cb];                              \
    }                                                                       \
  } while(0)

  // re-zero the 68 pad rows (clobbered when buffer served as C-tile)
  #define ZPAD(buf) do {                                                    \
    for (int i_ = sp; i_ < 544; i_ += 256){                                 \
      int r_ = i_ >> 3, q_ = i_ & 7, row_;                                  \
      if (r_ < 18)      row_ = r_;                                          \
      else if (r_ < 34) row_ = 18*(r_ - 17);                                \
      else if (r_ < 50) row_ = 18*(r_ - 33) + 17;                           \
      else              row_ = 306 + (r_ - 50);                             \
      *(uint4*)((char*)(buf) + row_*128 + q_*16) = make_uint4(0u,0u,0u,0u); \
    }                                                                       \
  } while(0)

  #define LOADB(s, B, Wt) do {                                              \
    _Pragma("unroll")                                                       \
    for (int n_ = 0; n_ < 4; ++n_)                                          \
      B[n_] = *(const f16x8*)((Wt) + ((((s)*4 + n_)*64) + lane)*8);         \
  } while(0)

  #define STEP(s, B, buf) do {                                              \
    int tap_ = (s) >> 1, kk_ = (s) & 1;                                     \
    int dy_ = tap_ / 3, dx_ = tap_ - dy_*3;                                 \
    f16x8 af_[4];                                                           \
    _Pragma("unroll")                                                       \
    for (int m_ = 0; m_ < 4; ++m_){                                         \
      int pp_ = (pyb + m_ + dy_)*18 + lr + dx_;                             \
      unsigned slot_ = ((unsigned)(kk_*4 + lg) + (unsigned)pp_) & 7u;       \
      af_[m_] = *(const f16x8*)((const char*)(buf)                          \
                 + (unsigned)(pp_*128) + (slot_ << 4));                     \
    }                                                                       \
    _Pragma("unroll")                                                       \
    for (int m_ = 0; m_ < 4; ++m_)                                          \
      _Pragma("unroll")                                                     \
      for (int n_ = 0; n_ < 4; ++n_)                                        \
        acc[m_][n_] = __builtin_amdgcn_mfma_f32_16x16x32_f16(               \
            af_[m_], B[n_], acc[m_][n_], 0, 0, 0);                          \
  } while(0)

  // ---- prologue: stage frame 0, zero both buffers ----
  if (stagew) LOADCVT(gf0);
  for (int i = tid; i < 2592; i += 512){
    *(uint4*)((char*)xT0 + i*16) = make_uint4(0u,0u,0u,0u);
    *(uint4*)((char*)xT1 + i*16) = make_uint4(0u,0u,0u,0u);
  }
  __syncthreads();
  if (stagew) PACKW(xT0);
  __syncthreads();

  // ---- main pipeline ----
  #pragma unroll 1
  for (int f = 0; f < F; ++f){
    const int gf = gf0 + f;
    const int wh = gf >> 9, frame = gf & 511;
    const u16* Wt = Wt_base + wh*wt_stride;
    const float* bias = (wh==0)?b0:(wh==1)?b1:b2;
    u16* cur = (f & 1) ? xT1 : xT0;
    u16* nxt = (f & 1) ? xT0 : xT1;

    if (stagew && f + 1 < F) LOADCVT(gf + 1);

    f32x4 acc[4][4];
    if (!stagew){
      #pragma unroll
      for (int n = 0; n < 4; ++n){
        float b = bias[n*16 + lr];
        #pragma unroll
        for (int m = 0; m < 4; ++m){
          acc[m][n][0] = b; acc[m][n][1] = b; acc[m][n][2] = b; acc[m][n][3] = b;
        }
      }
      f16x8 Ba[4], Bb[4];
      LOADB(0, Ba, Wt);
      #pragma unroll 1
      for (int it = 0; it < 9; ++it){
        LOADB(it*2 + 1, Bb, Wt);
        STEP(it*2, Ba, cur);
        if (it < 8) LOADB(it*2 + 2, Ba, Wt);
        STEP(it*2 + 1, Bb, cur);
      }
    }
    __syncthreads();                           // B1: K-loop done; cur = tile

    char* tc = (char*)cur;
    if (OUT_PROJ){
      if (!stagew){
        #pragma unroll
        for (int n = 0; n < 4; ++n){
          int co = n*16 + lr;
          #pragma unroll
          for (int m = 0; m < 4; ++m){
            int px0 = w*64 + m*16 + lg*4;
            int s = px0 >> 3;
            unsigned aw = (unsigned)(co*512) + (unsigned)((s ^ (co & 7)) << 4)
                          + (unsigned)((px0 & 7) * 2);
            u16x4 o4;
            #pragma unroll
            for (int r = 0; r < 4; ++r) o4[r] = f2h(acc[m][n][r]);
            *(u16x4*)(tc + aw) = o4;
          }
        }
      } else if (f + 1 < F){
        ZPAD(nxt); PACKW(nxt);
      }
      __syncthreads();                         // B2
      if (!stagew){
        u16* d = (u16*)((wh==0)?d0:(wh==1)?d1:d2);
        const int b = frame >> 8, sq = frame & 255;
        #pragma unroll
        for (int i = 0; i < 8; ++i){
          int c = w*8 + i;
          int co = c*2 + (lane >> 5);
          int pxo = (lane & 31) * 8;
          unsigned ld = (unsigned)(co*512) + (unsigned)(((lane & 31) ^ (co & 7)) << 4);
          uint4 v = *(const uint4*)(tc + ld);
          int h = co >> 3, dk = co & 7;
          u16* gp = d + ((size_t)((b*8 + h)*256 + sq))*2048 + dk*256 + pxo;
          *(uint4*)gp = v;
        }
      }
      __syncthreads();                         // B3
    } else {
      float* dfr = (float*)d0 + (size_t)frame * 16384;
      // ph0
      if (!stagew && (w >> 1) == 0){
        #pragma unroll
        for (int n = 0; n < 4; ++n){
          int co = n*16 + lr;
          #pragma unroll
          for (int m = 0; m < 4; ++m){
            int pxl = (w & 1)*64 + m*16 + lg*4;
            int s = pxl >> 2;
            unsigned aw = (unsigned)(co*512) + (unsigned)((s ^ (co & 7)) << 4);
            *(f32x4*)(tc + aw) = acc[m][n];
          }
        }
      }
      if (stagew && f + 1 < F){ ZPAD(nxt); PACKW(nxt); }
      __syncthreads();                         // B2
      if (!stagew){
        #pragma unroll
        for (int i = 0; i < 8; ++i){
          int c = w*8 + i;
          int co = c*2 + (lane >> 5);
          int pxl = (lane & 31) * 4;
          unsigned ld = (unsigned)(co*512) + (unsigned)(((lane & 31) ^ (co & 7)) << 4);
          f32x4 v = *(const f32x4*)(tc + ld);
          *(f32x4*)(dfr + co*256 + pxl) = v;
        }
      }
      __syncthreads();                         // B3
      if (!stagew && (w >> 1) == 1){
        #pragma unroll
        for (int n = 0; n < 4; ++n){
          int co = n*16 + lr;
          #pragma unroll
          for (int m = 0; m < 4; ++m){
            int pxl = (w & 1)*64 + m*16 + lg*4;
            int s = pxl >> 2;
            unsigned aw = (unsigned)(co*512) + (unsigned)((s ^ (co & 7)) << 4);
            *(f32x4*)(tc + aw) = acc[m][n];
          }
        }
      }
      __syncthreads();                         // B4
      if (!stagew){
        #pragma unroll
        for (int i = 0; i < 8; ++i){
          int c = w*8 + i;
          int co = c*2 + (lane >> 5);
          int pxl = (lane & 31) * 4;
          unsigned ld = (unsigned)(co*512) + (unsigned)(((lane & 31) ^ (co & 7)) << 4);
          f32x4 v = *(const f32x4*)(tc + ld);
          *(f32x4*)(dfr + co*256 + 128 + pxl) = v;
        }
      }
      __syncthreads();                         // B5
    }
  }
  #undef LOADCVT
  #undef PACKW
  #undef ZPAD
  #undef LOADB
  #undef STEP
}

// ---------------------------------------------------------------------------
// V transpose: vh [bh][s][2048] -> vt [bh][d][256]  (unchanged, verified)
// ---------------------------------------------------------------------------
__global__ __launch_bounds__(256) void transpose_v(
    const u16* __restrict__ vh, u16* __restrict__ vt)
{
  __shared__ u16 tile[64][72];
  const int tid = threadIdx.x;
  const int dt = blockIdx.x, st = blockIdx.y, bh = blockIdx.z;
  {
    int r = tid >> 2, c4 = tid & 3;
    const u16* src = vh + ((size_t)(bh*256 + st*64 + r))*2048 + dt*64 + c4*16;
    uint4 v0 = *(const uint4*)src;
    uint4 v1 = *(const uint4*)(src + 8);
    *(uint4*)&tile[r][c4*16]     = v0;
    *(uint4*)&tile[r][c4*16 + 8] = v1;
  }
  __syncthreads();
  {
    int dr = tid >> 2, s4 = tid & 3;
    u16 tmp[16];
    #pragma unroll
    for (int i = 0; i < 16; ++i) tmp[i] = tile[s4*16 + i][dr];
    u16* dstp = vt + ((size_t)(bh*2048 + dt*64 + dr))*256 + st*64 + s4*16;
    *(uint4*)dstp       = *(uint4*)&tmp[0];
    *(uint4*)(dstp + 8) = *(uint4*)&tmp[8];
  }
}

// ---------------------------------------------------------------------------
// Attention v3 (R12 champion, unchanged, fp16)
// ---------------------------------------------------------------------------
__global__ __launch_bounds__(512, 2) void attn_kernel(
    const u16* __restrict__ qh, const u16* __restrict__ kh,
    const u16* __restrict__ vt, u16* __restrict__ obuf)
{
  const float SCALE = 0.022097086912079608f;   // 1/sqrt(2048)
  __shared__ __align__(16) u16 Qs[16*2048];
  __shared__ __align__(16) u16 Kb[2][16384];
  __shared__ __align__(16) u16 P[16*256];
  __shared__ float redA[8][16];
  __shared__ float redB[8][16];

  const int tid = threadIdx.x;
  const int w = tid >> 6, lane = tid & 63, lr = lane & 15, lg = lane >> 4;

  const int id = blockIdx.x;
  const int xcd = id & 7, j = id >> 3;
  const int bh = xcd + 8*(j & 1), qt = j >> 1;
  const int q0 = qt * 16, b = bh >> 3, h = bh & 7;

  const u16* Qg = qh + ((size_t)(bh*256 + q0))*2048;
  const u16* Kg = kh + (size_t)bh * 256 * 2048;
  const u16* Vg = vt + (size_t)bh * 2048 * 256;

  const int spK = (lane & 7) ^ ((lane >> 3) & 7);
  #define STAGE_K(c, buf)                                                   \
    _Pragma("unroll")                                                       \
    for (int r_ = 0; r_ < 4; ++r_)                                          \
      cp16_async(Kg + (size_t)(w*32 + r_*8 + (lane>>3))*2048 + (c)*64 + spK*8, \
                 (buf) + w*2048 + r_*512);

  #define STAGE_V(c, buf)                                                   \
    _Pragma("unroll")                                                       \
    for (int r_ = 0; r_ < 8; ++r_){                                         \
      int rl_ = w*16 + r_*2 + (lane>>5);                                    \
      int sp_ = (lane & 31) ^ (rl_ & 7);                                    \
      cp16_async(Vg + (size_t)((c)*128 + rl_)*256 + sp_*8,                  \
                 (buf) + w*4096 + r_*512);                                  \
    }

  #pragma unroll
  for (int r = 0; r < 8; ++r){
    int t = r*64 + lane;
    int row = w*2 + (t >> 8);
    int dp = t & 255;
    int sp = (dp & ~7) | ((dp & 7) ^ (row & 7));
    cp16_async(Qg + (size_t)row*2048 + sp*8, Qs + w*4096 + r*512);
  }
  STAGE_K(0, Kb[0]);
  __syncthreads();

  const f32x4 zero4 = {0.f, 0.f, 0.f, 0.f};
  f32x4 sacc[2] = {zero4, zero4};
  #pragma unroll 1
  for (int c = 0; c < 32; ++c){
    if (c < 31) STAGE_K(c+1, Kb[(c+1)&1]);
    const u16* kb = Kb[c&1];
    #pragma unroll
    for (int d2 = 0; d2 < 2; ++d2){
      unsigned aoff = (((unsigned)lr << 12) + (unsigned)(c*128 + d2*64 + lg*16))
                      ^ (unsigned)((lr & 7) << 4);
      f16x8 a = *(const f16x8*)((const char*)Qs + aoff);
      #pragma unroll
      for (int n = 0; n < 2; ++n){
        int row = w*32 + n*16 + lr;
        const u16* kp = kb + row*64 + (((d2*4 + lg) ^ (row & 7)) << 3);
        f16x8 bk = *(const f16x8*)kp;
        sacc[n] = __builtin_amdgcn_mfma_f32_16x16x32_f16(a, bk, sacc[n], 0,0,0);
      }
    }
    __syncthreads();
  }

  float mx[4];
  #pragma unroll
  for (int r = 0; r < 4; ++r){
    float vv = fmaxf(sacc[0][r], sacc[1][r]);
    #pragma unroll
    for (int off = 1; off < 16; off <<= 1) vv = fmaxf(vv, __shfl_xor(vv, off));
    mx[r] = vv;
  }
  if (lr == 0){
    #pragma unroll
    for (int r = 0; r < 4; ++r) redA[w][lg*4 + r] = mx[r];
  }
  __syncthreads();
  #pragma unroll
  for (int r = 0; r < 4; ++r){
    int row = lg*4 + r;
    float vv = redA[0][row];
    #pragma unroll
    for (int ww = 1; ww < 8; ++ww) vv = fmaxf(vv, redA[ww][row]);
    mx[r] = vv;
  }

  const int kbase = w * 32;
  float sm[4] = {0.f, 0.f, 0.f, 0.f};
  #pragma unroll
  for (int n = 0; n < 2; ++n)
    #pragma unroll
    for (int r = 0; r < 4; ++r){
      float pv = __expf((sacc[n][r] - mx[r]) * SCALE);
      sm[r] += pv;
      int row = lg*4 + r;
      int col = kbase + n*16 + lr;
      unsigned off = (((unsigned)row << 9) + ((unsigned)col << 1))
                     ^ (unsigned)((row & 7) << 4);
      *(u16*)((char*)P + off) = f2h(pv);
    }
  #pragma unroll
  for (int r = 0; r < 4; ++r){
    float vv = sm[r];
    #pragma unroll
    for (int off = 1; off < 16; off <<= 1) vv += __shfl_xor(vv, off);
    sm[r] = vv;
  }
  if (lr == 0){
    #pragma unroll
    for (int r = 0; r < 4; ++r) redB[w][lg*4 + r] = sm[r];
  }
  __syncthreads();
  float rs[4];
  #pragma unroll
  for (int r = 0; r < 4; ++r){
    int row = lg*4 + r;
    float s = redB[0][row];
    #pragma unroll
    for (int ww = 1; ww < 8; ++ww) s += redB[ww][row];
    rs[r] = 1.0f / s;
  }

  u16* Vb0 = Qs;
  u16* Vb1 = &Kb[0][0];
  STAGE_V(0, Vb0);
  __syncthreads();
  #pragma unroll 1
  for (int c = 0; c < 16; ++c){
    if (c < 15){
      u16* nbuf = ((c+1) & 1) ? Vb1 : Vb0;
      STAGE_V(c+1, nbuf);
    }
    const u16* vb = (c & 1) ? Vb1 : Vb0;
    f32x4 oacc = zero4;
    #pragma unroll
    for (int kt = 0; kt < 8; ++kt){
      unsigned poff = (((unsigned)lr << 9) + (unsigned)(kt*64 + lg*16))
                      ^ (unsigned)((lr & 7) << 4);
      f16x8 pa = *(const f16x8*)((const char*)P + poff);
      int row = w*16 + lr;
      const u16* vp = vb + row*256 + (((kt*4 + lg) ^ (row & 7)) << 3);
      f16x8 bv = *(const f16x8*)vp;
      oacc = __builtin_amdgcn_mfma_f32_16x16x32_f16(pa, bv, oacc, 0,0,0);
    }
    #pragma unroll
    for (int r = 0; r < 4; ++r){
      float o = oacc[r] * rs[r];
      int qrow = q0 + lg*4 + r;
      int d = c*128 + w*16 + lr;
      int frame = b*256 + qrow;
      int cdim = h*8 + (d >> 8);
      obuf[((size_t)(frame*64 + cdim))*256 + (d & 255)] = f2h(o);
    }
    __syncthreads();
  }
  #undef STAGE_K
  #undef STAGE_V
}

// ---------------------------------------------------------------------------
extern "C" void kernel_launch(void* const* d_in, const int* in_sizes, int n_in,
                              void* d_out, int out_size, void* d_ws, size_t ws_size,
                              hipStream_t stream)
{
  const float* q  = (const float*)d_in[0];
  const float* k  = (const float*)d_in[1];
  const float* v  = (const float*)d_in[2];
  const float* Wq = (const float*)d_in[3];
  const float* bq = (const float*)d_in[4];
  const float* Wk = (const float*)d_in[5];
  const float* bk = (const float*)d_in[6];
  const float* Wv = (const float*)d_in[7];
  const float* bv = (const float*)d_in[8];
  const float* Wo = (const float*)d_in[9];
  const float* bo = (const float*)d_in[10];
  float* out = (float*)d_out;

  // Workspace (64 MB): qh[0,16M) kh[16,32M) vh[32,48M) vt[48,64M)
  char* ws = (char*)d_ws;
  u16* qh = (u16*)(ws);
  u16* kh = (u16*)(ws + (size_t)16*1024*1024);
  u16* vh = (u16*)(ws + (size_t)32*1024*1024);
  u16* vt = (u16*)(ws + (size_t)48*1024*1024);
  u16* obuf = vh;          // attn output frames (vh dead after transpose_v)
  u16* Wt3  = vt;          // weight packs; dead before transpose_v clobbers
  u16* WtO  = qh;          // qh dead after attn

  prep_w3<<<dim3(144, 3), dim3(256), 0, stream>>>(Wq, Wk, Wv, Wt3);
  conv_pipe<true, true, 6><<<dim3(256), dim3(512), 0, stream>>>(
      q, k, v, Wt3, 36864, bq, bk, bv, qh, kh, vh);
  transpose_v<<<dim3(32, 4, 16), dim3(256), 0, stream>>>(vh, vt);
  attn_kernel<<<dim3(256), dim3(512), 0, stream>>>(qh, kh, vt, obuf);
  prep_w<<<dim3(144), dim3(256), 0, stream>>>(Wo, WtO);
  conv_pipe<false, false, 2><<<dim3(256), dim3(512), 0, stream>>>(
      obuf, obuf, obuf, WtO, 0, bo, bo, bo, out, out, out);
}

// Round 16
// 127.005 us; speedup vs baseline: 1.0455x; 1.0455x over previous
//
#include <hip/hip_runtime.h>
#include <hip/hip_bf16.h>
#include <hip/hip_fp16.h>

typedef unsigned short u16;
typedef _Float16 f16x8 __attribute__((ext_vector_type(8)));
typedef u16 u16x8 __attribute__((ext_vector_type(8)));
typedef u16 u16x4 __attribute__((ext_vector_type(4)));
typedef float f32x4 __attribute__((ext_vector_type(4)));

__device__ __forceinline__ u16 f2h(float f){
  __half h = __float2half(f);
  return *(u16*)&h;
}

// async 16B global -> LDS (dest = wave-uniform base + lane*16; src per-lane)
__device__ __forceinline__ void cp16_async(const u16* g, u16* l){
  __builtin_amdgcn_global_load_lds(
      (const __attribute__((address_space(1))) unsigned int*)g,
      (__attribute__((address_space(3))) unsigned int*)l,
      16, 0, 0);
}

// ---------------------------------------------------------------------------
// Weight prep (unchanged, verified): W f32 [co][ci][3][3] ->
// Wt fp16 frag-linear  Wt[((s*4+n)*64 + lane)*8 + j],  s=tap*2+(ci/32)
// ---------------------------------------------------------------------------
__device__ __forceinline__ void prep_w_body(const float* W, u16* Wt, int i){
  if (i >= 36864) return;
  int co = i / 576, rem = i % 576, ci = rem / 9, tap = rem % 9;
  int n = co >> 4, lr = co & 15, kk = ci >> 5, lg = (ci >> 3) & 3, j = ci & 7;
  int s = tap*2 + kk;
  Wt[(((s*4 + n)*64) + lg*16 + lr)*8 + j] = f2h(W[i]);
}

__global__ __launch_bounds__(256) void prep_w3(
    const float* __restrict__ Wq, const float* __restrict__ Wk,
    const float* __restrict__ Wv, u16* __restrict__ Wt)
{
  int which = blockIdx.y;
  const float* W = (which == 0) ? Wq : (which == 1) ? Wk : Wv;
  prep_w_body(W, Wt + which*36864, blockIdx.x * 256 + threadIdx.x);
}

__global__ __launch_bounds__(256) void prep_w(
    const float* __restrict__ W, u16* __restrict__ Wt)
{
  prep_w_body(W, Wt, blockIdx.x * 256 + threadIdx.x);
}

// ---------------------------------------------------------------------------
// conv3 v14: HALF-FRAME blocks. Grid 3072 = frame x 2 halves. Each block
// computes 8 image rows (128 px), stages 9 rows (1-row halo), LDS 22.5 KB
// -> 6 blocks/CU of independent, phase-drifting pipelines.
// Local padded buffer: 10 rows x 18 cols x 64 ci fp16, swizzled as before
// (slot = (cb + lpp) & 7). K-loop/MFMA order identical to R12 per output.
// ---------------------------------------------------------------------------
__global__ __launch_bounds__(256, 6) void conv3_half(
    const float* __restrict__ q, const float* __restrict__ k,
    const float* __restrict__ v, const u16* __restrict__ Wt3,
    const float* __restrict__ bq, const float* __restrict__ bk,
    const float* __restrict__ bv,
    u16* __restrict__ qh, u16* __restrict__ kh, u16* __restrict__ vh)
{
  __shared__ __align__(16) u16 xT[180 * 64];     // 23040 B
  const int tid = threadIdx.x;
  const int bx = blockIdx.x;
  const int gf = bx >> 1, half = bx & 1;
  const int which = gf >> 9, frame = gf & 511;
  const float* x = (which == 0) ? q : (which == 1) ? k : v;
  const float* bias = (which == 0) ? bq : (which == 1) ? bk : bv;
  u16* dout = (which == 0) ? qh : (which == 1) ? kh : vh;
  const u16* Wt = Wt3 + which*36864;
  const float* xf = x + (size_t)frame * 16384;

  // ---- stage: 9 rows (8 compute + 1 halo), tid<144 = one pixel each ----
  float xvf[64];
  int lpp = 0;
  if (tid < 144){
    int lyr = tid >> 4, px = tid & 15;
    int gy = (half == 0) ? lyr : (7 + lyr);      // global image row
    int lpy = gy - half*8 + 1;                   // local padded row 0..9
    lpp = lpy*18 + px + 1;
    int p_img = gy*16 + px;
    #pragma unroll
    for (int c = 0; c < 64; ++c) xvf[c] = xf[c*256 + p_img];
  }

  for (int i = tid; i < 1440; i += 256)          // zero all 23040 B
    *(uint4*)((char*)xT + i*16) = make_uint4(0u, 0u, 0u, 0u);
  __syncthreads();

  if (tid < 144){
    #pragma unroll
    for (int cb = 0; cb < 8; ++cb){
      u16x8 pk;
      #pragma unroll
      for (int j = 0; j < 8; ++j) pk[j] = f2h(xvf[cb*8 + j]);
      unsigned off = (unsigned)(lpp*128) + ((((unsigned)cb + (unsigned)lpp) & 7u) << 4);
      *(u16x8*)((char*)xT + off) = pk;
    }
  }
  __syncthreads();

  const int w = tid >> 6, lane = tid & 63, lr = lane & 15, lg = lane >> 4;
  const int pyb = w * 2;                         // wave's 2 local px-rows

  f32x4 acc[2][4];
  #pragma unroll
  for (int n = 0; n < 4; ++n){
    float b = bias[n*16 + lr];
    #pragma unroll
    for (int m = 0; m < 2; ++m){
      acc[m][n][0] = b; acc[m][n][1] = b; acc[m][n][2] = b; acc[m][n][3] = b;
    }
  }

  #define LOADB(s, B) do {                                                  \
    _Pragma("unroll")                                                       \
    for (int n_ = 0; n_ < 4; ++n_)                                          \
      B[n_] = *(const f16x8*)(Wt + ((((s)*4 + n_)*64) + lane)*8);           \
  } while(0)

  // local padded row for output row ly, tap dy is (ly + dy); cols as before
  #define STEP(s, B) do {                                                   \
    int tap_ = (s) >> 1, kk_ = (s) & 1;                                     \
    int dy_ = tap_ / 3, dx_ = tap_ - dy_*3;                                 \
    f16x8 af_[2];                                                           \
    _Pragma("unroll")                                                       \
    for (int m_ = 0; m_ < 2; ++m_){                                         \
      int pp_ = (pyb + m_ + dy_)*18 + lr + dx_;                             \
      unsigned slot_ = ((unsigned)(kk_*4 + lg) + (unsigned)pp_) & 7u;       \
      af_[m_] = *(const f16x8*)((const char*)xT                             \
                 + (unsigned)(pp_*128) + (slot_ << 4));                     \
    }                                                                       \
    _Pragma("unroll")                                                       \
    for (int m_ = 0; m_ < 2; ++m_)                                          \
      _Pragma("unroll")                                                     \
      for (int n_ = 0; n_ < 4; ++n_)                                        \
        acc[m_][n_] = __builtin_amdgcn_mfma_f32_16x16x32_f16(               \
            af_[m_], B[n_], acc[m_][n_], 0, 0, 0);                          \
  } while(0)

  f16x8 Ba[4], Bb[4];
  LOADB(0, Ba);
  #pragma unroll 1
  for (int it = 0; it < 9; ++it){
    LOADB(it*2 + 1, Bb);
    STEP(it*2, Ba);
    if (it < 8) LOADB(it*2 + 2, Ba);
    STEP(it*2 + 1, Bb);
  }
  #undef LOADB
  #undef STEP

  // ---- coalesced epilogue: xT dead -> [co][128 px] fp16 tile (16 KB) ----
  __syncthreads();
  char* xTc = (char*)xT;
  #pragma unroll
  for (int n = 0; n < 4; ++n){
    int co = n*16 + lr;
    #pragma unroll
    for (int m = 0; m < 2; ++m){
      int px0 = w*32 + m*16 + lg*4;              // local px 0..127
      int s = px0 >> 3;                          // slot 0..15
      unsigned aw = (unsigned)(co*256) + (unsigned)((s ^ (co & 7)) << 4)
                    + (unsigned)((px0 & 7) * 2);
      u16x4 o4;
      #pragma unroll
      for (int r = 0; r < 4; ++r) o4[r] = f2h(acc[m][n][r]);
      *(u16x4*)(xTc + aw) = o4;
    }
  }
  __syncthreads();
  {
    const int b = frame >> 8, sq = frame & 255;
    #pragma unroll
    for (int i = 0; i < 4; ++i){
      int c = w*4 + i;                           // 1KB chunk 0..15
      int co = c*4 + (lane >> 4);
      int pxo = (lane & 15) * 8;
      unsigned ld = (unsigned)(co*256) + (unsigned)(((lane & 15) ^ (co & 7)) << 4);
      uint4 vv = *(const uint4*)(xTc + ld);
      int h = co >> 3, dk = co & 7;
      u16* gp = dout + ((size_t)((b*8 + h)*256 + sq))*2048 + dk*256
                + half*128 + pxo;
      *(uint4*)gp = vv;
    }
  }
}

// ---------------------------------------------------------------------------
// conv_out (exact R12 body: scalar u16 loads + frag-linear B + R10 epilogue)
// ---------------------------------------------------------------------------
__global__ __launch_bounds__(256, 3) void conv_out_mfma(
    const u16* __restrict__ xin, const u16* __restrict__ Wt,
    const float* __restrict__ bias, float* __restrict__ out)
{
  __shared__ __align__(16) u16 xT[324 * 64];
  const int tid = threadIdx.x;
  const int frame = blockIdx.x;
  const int p = tid, py = p >> 4, px = p & 15;
  const int pp = (py + 1)*18 + px + 1;
  const u16* xb = xin + (size_t)frame * 16384;

  u16 xvu[64];
  #pragma unroll
  for (int c = 0; c < 64; ++c) xvu[c] = xb[c*256 + p];

  for (int i = tid; i < 2592; i += 256)
    *(uint4*)((char*)xT + i*16) = make_uint4(0u, 0u, 0u, 0u);
  __syncthreads();

  #pragma unroll
  for (int cb = 0; cb < 8; ++cb){
    u16x8 pk;
    #pragma unroll
    for (int j = 0; j < 8; ++j) pk[j] = xvu[cb*8 + j];
    unsigned off = (unsigned)(pp*128) + ((((unsigned)cb + (unsigned)pp) & 7u) << 4);
    *(u16x8*)((char*)xT + off) = pk;
  }
  __syncthreads();

  const int w = tid >> 6, lane = tid & 63, lr = lane & 15, lg = lane >> 4;
  const int pyb = w * 4;

  f32x4 acc[4][4];
  #pragma unroll
  for (int n = 0; n < 4; ++n){
    float b = bias[n*16 + lr];
    #pragma unroll
    for (int m = 0; m < 4; ++m){
      acc[m][n][0] = b; acc[m][n][1] = b; acc[m][n][2] = b; acc[m][n][3] = b;
    }
  }

  #define LOADB(s, B) do {                                                  \
    _Pragma("unroll")                                                       \
    for (int n_ = 0; n_ < 4; ++n_)                                          \
      B[n_] = *(const f16x8*)(Wt + ((((s)*4 + n_)*64) + lane)*8);           \
  } while(0)

  #define STEP(s, B) do {                                                   \
    int tap_ = (s) >> 1, kk_ = (s) & 1;                                     \
    int dy_ = tap_ / 3, dx_ = tap_ - dy_*3;                                 \
    f16x8 af_[4];                                                           \
    _Pragma("unroll")                                                       \
    for (int m_ = 0; m_ < 4; ++m_){                                         \
      int pp_ = (pyb + m_ + dy_)*18 + lr + dx_;                             \
      unsigned slot_ = ((unsigned)(kk_*4 + lg) + (unsigned)pp_) & 7u;       \
      af_[m_] = *(const f16x8*)((const char*)xT                             \
                 + (unsigned)(pp_*128) + (slot_ << 4));                     \
    }                                                                       \
    _Pragma("unroll")                                                       \
    for (int m_ = 0; m_ < 4; ++m_)                                          \
      _Pragma("unroll")                                                     \
      for (int n_ = 0; n_ < 4; ++n_)                                        \
        acc[m_][n_] = __builtin_amdgcn_mfma_f32_16x16x32_f16(               \
            af_[m_], B[n_], acc[m_][n_], 0, 0, 0);                          \
  } while(0)

  f16x8 Ba[4], Bb[4];
  LOADB(0, Ba);
  #pragma unroll 1
  for (int it = 0; it < 9; ++it){
    LOADB(it*2 + 1, Bb);
    STEP(it*2, Ba);
    if (it < 8) LOADB(it*2 + 2, Ba);
    STEP(it*2 + 1, Bb);
  }
  #undef LOADB
  #undef STEP

  __syncthreads();
  char* xTc = (char*)xT;
  float* dfr = out + (size_t)frame * 16384;
  #pragma unroll
  for (int ph2 = 0; ph2 < 2; ++ph2){
    if ((w >> 1) == ph2){
      #pragma unroll
      for (int n = 0; n < 4; ++n){
        int co = n*16 + lr;
        #pragma unroll
        for (int m = 0; m < 4; ++m){
          int pxl = (w & 1)*64 + m*16 + lg*4;
          int s = pxl >> 2;
          unsigned aw = (unsigned)(co*512) + (unsigned)((s ^ (co & 7)) << 4);
          *(f32x4*)(xTc + aw) = acc[m][n];
        }
      }
    }
    __syncthreads();
    #pragma unroll
    for (int i = 0; i < 8; ++i){
      int c = w*8 + i;
      int co = c*2 + (lane >> 5);
      int pxl = (lane & 31) * 4;
      unsigned ld = (unsigned)(co*512) + (unsigned)(((lane & 31) ^ (co & 7)) << 4);
      f32x4 v = *(const f32x4*)(xTc + ld);
      *(f32x4*)(dfr + co*256 + ph2*128 + pxl) = v;
    }
    if (ph2 == 0) __syncthreads();
  }
}

// ---------------------------------------------------------------------------
// V transpose: vh [bh][s][2048] -> vt [bh][d][256]  (unchanged, verified)
// ---------------------------------------------------------------------------
__global__ __launch_bounds__(256) void transpose_v(
    const u16* __restrict__ vh, u16* __restrict__ vt)
{
  __shared__ u16 tile[64][72];
  const int tid = threadIdx.x;
  const int dt = blockIdx.x, st = blockIdx.y, bh = blockIdx.z;
  {
    int r = tid >> 2, c4 = tid & 3;
    const u16* src = vh + ((size_t)(bh*256 + st*64 + r))*2048 + dt*64 + c4*16;
    uint4 v0 = *(const uint4*)src;
    uint4 v1 = *(const uint4*)(src + 8);
    *(uint4*)&tile[r][c4*16]     = v0;
    *(uint4*)&tile[r][c4*16 + 8] = v1;
  }
  __syncthreads();
  {
    int dr = tid >> 2, s4 = tid & 3;
    u16 tmp[16];
    #pragma unroll
    for (int i = 0; i < 16; ++i) tmp[i] = tile[s4*16 + i][dr];
    u16* dstp = vt + ((size_t)(bh*2048 + dt*64 + dr))*256 + st*64 + s4*16;
    *(uint4*)dstp       = *(uint4*)&tmp[0];
    *(uint4*)(dstp + 8) = *(uint4*)&tmp[8];
  }
}

// ---------------------------------------------------------------------------
// Attention v3 (R12 champion, unchanged, fp16)
// ---------------------------------------------------------------------------
__global__ __launch_bounds__(512, 2) void attn_kernel(
    const u16* __restrict__ qh, const u16* __restrict__ kh,
    const u16* __restrict__ vt, u16* __restrict__ obuf)
{
  const float SCALE = 0.022097086912079608f;   // 1/sqrt(2048)
  __shared__ __align__(16) u16 Qs[16*2048];
  __shared__ __align__(16) u16 Kb[2][16384];
  __shared__ __align__(16) u16 P[16*256];
  __shared__ float redA[8][16];
  __shared__ float redB[8][16];

  const int tid = threadIdx.x;
  const int w = tid >> 6, lane = tid & 63, lr = lane & 15, lg = lane >> 4;

  const int id = blockIdx.x;
  const int xcd = id & 7, j = id >> 3;
  const int bh = xcd + 8*(j & 1), qt = j >> 1;
  const int q0 = qt * 16, b = bh >> 3, h = bh & 7;

  const u16* Qg = qh + ((size_t)(bh*256 + q0))*2048;
  const u16* Kg = kh + (size_t)bh * 256 * 2048;
  const u16* Vg = vt + (size_t)bh * 2048 * 256;

  const int spK = (lane & 7) ^ ((lane >> 3) & 7);
  #define STAGE_K(c, buf)                                                   \
    _Pragma("unroll")                                                       \
    for (int r_ = 0; r_ < 4; ++r_)                                          \
      cp16_async(Kg + (size_t)(w*32 + r_*8 + (lane>>3))*2048 + (c)*64 + spK*8, \
                 (buf) + w*2048 + r_*512);

  #define STAGE_V(c, buf)                                                   \
    _Pragma("unroll")                                                       \
    for (int r_ = 0; r_ < 8; ++r_){                                         \
      int rl_ = w*16 + r_*2 + (lane>>5);                                    \
      int sp_ = (lane & 31) ^ (rl_ & 7);                                    \
      cp16_async(Vg + (size_t)((c)*128 + rl_)*256 + sp_*8,                  \
                 (buf) + w*4096 + r_*512);                                  \
    }

  #pragma unroll
  for (int r = 0; r < 8; ++r){
    int t = r*64 + lane;
    int row = w*2 + (t >> 8);
    int dp = t & 255;
    int sp = (dp & ~7) | ((dp & 7) ^ (row & 7));
    cp16_async(Qg + (size_t)row*2048 + sp*8, Qs + w*4096 + r*512);
  }
  STAGE_K(0, Kb[0]);
  __syncthreads();

  const f32x4 zero4 = {0.f, 0.f, 0.f, 0.f};
  f32x4 sacc[2] = {zero4, zero4};
  #pragma unroll 1
  for (int c = 0; c < 32; ++c){
    if (c < 31) STAGE_K(c+1, Kb[(c+1)&1]);
    const u16* kb = Kb[c&1];
    #pragma unroll
    for (int d2 = 0; d2 < 2; ++d2){
      unsigned aoff = (((unsigned)lr << 12) + (unsigned)(c*128 + d2*64 + lg*16))
                      ^ (unsigned)((lr & 7) << 4);
      f16x8 a = *(const f16x8*)((const char*)Qs + aoff);
      #pragma unroll
      for (int n = 0; n < 2; ++n){
        int row = w*32 + n*16 + lr;
        const u16* kp = kb + row*64 + (((d2*4 + lg) ^ (row & 7)) << 3);
        f16x8 bk = *(const f16x8*)kp;
        sacc[n] = __builtin_amdgcn_mfma_f32_16x16x32_f16(a, bk, sacc[n], 0,0,0);
      }
    }
    __syncthreads();
  }

  float mx[4];
  #pragma unroll
  for (int r = 0; r < 4; ++r){
    float vv = fmaxf(sacc[0][r], sacc[1][r]);
    #pragma unroll
    for (int off = 1; off < 16; off <<= 1) vv = fmaxf(vv, __shfl_xor(vv, off));
    mx[r] = vv;
  }
  if (lr == 0){
    #pragma unroll
    for (int r = 0; r < 4; ++r) redA[w][lg*4 + r] = mx[r];
  }
  __syncthreads();
  #pragma unroll
  for (int r = 0; r < 4; ++r){
    int row = lg*4 + r;
    float vv = redA[0][row];
    #pragma unroll
    for (int ww = 1; ww < 8; ++ww) vv = fmaxf(vv, redA[ww][row]);
    mx[r] = vv;
  }

  const int kbase = w * 32;
  float sm[4] = {0.f, 0.f, 0.f, 0.f};
  #pragma unroll
  for (int n = 0; n < 2; ++n)
    #pragma unroll
    for (int r = 0; r < 4; ++r){
      float pv = __expf((sacc[n][r] - mx[r]) * SCALE);
      sm[r] += pv;
      int row = lg*4 + r;
      int col = kbase + n*16 + lr;
      unsigned off = (((unsigned)row << 9) + ((unsigned)col << 1))
                     ^ (unsigned)((row & 7) << 4);
      *(u16*)((char*)P + off) = f2h(pv);
    }
  #pragma unroll
  for (int r = 0; r < 4; ++r){
    float vv = sm[r];
    #pragma unroll
    for (int off = 1; off < 16; off <<= 1) vv += __shfl_xor(vv, off);
    sm[r] = vv;
  }
  if (lr == 0){
    #pragma unroll
    for (int r = 0; r < 4; ++r) redB[w][lg*4 + r] = sm[r];
  }
  __syncthreads();
  float rs[4];
  #pragma unroll
  for (int r = 0; r < 4; ++r){
    int row = lg*4 + r;
    float s = redB[0][row];
    #pragma unroll
    for (int ww = 1; ww < 8; ++ww) s += redB[ww][row];
    rs[r] = 1.0f / s;
  }

  u16* Vb0 = Qs;
  u16* Vb1 = &Kb[0][0];
  STAGE_V(0, Vb0);
  __syncthreads();
  #pragma unroll 1
  for (int c = 0; c < 16; ++c){
    if (c < 15){
      u16* nbuf = ((c+1) & 1) ? Vb1 : Vb0;
      STAGE_V(c+1, nbuf);
    }
    const u16* vb = (c & 1) ? Vb1 : Vb0;
    f32x4 oacc = zero4;
    #pragma unroll
    for (int kt = 0; kt < 8; ++kt){
      unsigned poff = (((unsigned)lr << 9) + (unsigned)(kt*64 + lg*16))
                      ^ (unsigned)((lr & 7) << 4);
      f16x8 pa = *(const f16x8*)((const char*)P + poff);
      int row = w*16 + lr;
      const u16* vp = vb + row*256 + (((kt*4 + lg) ^ (row & 7)) << 3);
      f16x8 bv = *(const f16x8*)vp;
      oacc = __builtin_amdgcn_mfma_f32_16x16x32_f16(pa, bv, oacc, 0,0,0);
    }
    #pragma unroll
    for (int r = 0; r < 4; ++r){
      float o = oacc[r] * rs[r];
      int qrow = q0 + lg*4 + r;
      int d = c*128 + w*16 + lr;
      int frame = b*256 + qrow;
      int cdim = h*8 + (d >> 8);
      obuf[((size_t)(frame*64 + cdim))*256 + (d & 255)] = f2h(o);
    }
    __syncthreads();
  }
  #undef STAGE_K
  #undef STAGE_V
}

// ---------------------------------------------------------------------------
extern "C" void kernel_launch(void* const* d_in, const int* in_sizes, int n_in,
                              void* d_out, int out_size, void* d_ws, size_t ws_size,
                              hipStream_t stream)
{
  const float* q  = (const float*)d_in[0];
  const float* k  = (const float*)d_in[1];
  const float* v  = (const float*)d_in[2];
  const float* Wq = (const float*)d_in[3];
  const float* bq = (const float*)d_in[4];
  const float* Wk = (const float*)d_in[5];
  const float* bk = (const float*)d_in[6];
  const float* Wv = (const float*)d_in[7];
  const float* bv = (const float*)d_in[8];
  const float* Wo = (const float*)d_in[9];
  const float* bo = (const float*)d_in[10];
  float* out = (float*)d_out;

  // Workspace (64 MB): qh[0,16M) kh[16,32M) vh[32,48M) vt[48,64M)
  char* ws = (char*)d_ws;
  u16* qh = (u16*)(ws);
  u16* kh = (u16*)(ws + (size_t)16*1024*1024);
  u16* vh = (u16*)(ws + (size_t)32*1024*1024);
  u16* vt = (u16*)(ws + (size_t)48*1024*1024);
  u16* obuf = vh;          // attn output frames (vh dead after transpose_v)
  u16* Wt3  = vt;          // weight packs; dead before transpose_v clobbers
  u16* WtO  = qh;          // qh dead after attn

  prep_w3<<<dim3(144, 3), dim3(256), 0, stream>>>(Wq, Wk, Wv, Wt3);
  conv3_half<<<dim3(3072), dim3(256), 0, stream>>>(q, k, v, Wt3, bq, bk, bv,
                                                   qh, kh, vh);
  transpose_v<<<dim3(32, 4, 16), dim3(256), 0, stream>>>(vh, vt);
  attn_kernel<<<dim3(256), dim3(512), 0, stream>>>(qh, kh, vt, obuf);
  prep_w<<<dim3(144), dim3(256), 0, stream>>>(Wo, WtO);
  conv_out_mfma<<<dim3(512), dim3(256), 0, stream>>>(obuf, WtO, bo, out);
}

// Round 17
// 115.498 us; speedup vs baseline: 1.1496x; 1.0996x over previous
//
#include <hip/hip_runtime.h>
#include <hip/hip_bf16.h>
#include <hip/hip_fp16.h>

typedef unsigned short u16;
typedef _Float16 f16x8 __attribute__((ext_vector_type(8)));
typedef u16 u16x8 __attribute__((ext_vector_type(8)));
typedef u16 u16x4 __attribute__((ext_vector_type(4)));
typedef float f32x4 __attribute__((ext_vector_type(4)));

__device__ __forceinline__ u16 f2h(float f){
  __half h = __float2half(f);
  return *(u16*)&h;
}

// async 16B global -> LDS (dest = wave-uniform base + lane*16; src per-lane)
__device__ __forceinline__ void cp16_async(const u16* g, u16* l){
  __builtin_amdgcn_global_load_lds(
      (const __attribute__((address_space(1))) unsigned int*)g,
      (__attribute__((address_space(3))) unsigned int*)l,
      16, 0, 0);
}

// ---------------------------------------------------------------------------
// Weight prep (verified): W f32 [co][ci][3][3] ->
// Wt fp16 frag-linear  Wt[((s*4+n)*64 + lane)*8 + j],  s=tap*2+(ci/32)
// ---------------------------------------------------------------------------
__device__ __forceinline__ void prep_w_body(const float* W, u16* Wt, int i){
  if (i >= 36864) return;
  int co = i / 576, rem = i % 576, ci = rem / 9, tap = rem % 9;
  int n = co >> 4, lr = co & 15, kk = ci >> 5, lg = (ci >> 3) & 3, j = ci & 7;
  int s = tap*2 + kk;
  Wt[(((s*4 + n)*64) + lg*16 + lr)*8 + j] = f2h(W[i]);
}

__global__ __launch_bounds__(256) void prep_w3(
    const float* __restrict__ Wq, const float* __restrict__ Wk,
    const float* __restrict__ Wv, u16* __restrict__ Wt)
{
  int which = blockIdx.y;
  const float* W = (which == 0) ? Wq : (which == 1) ? Wk : Wv;
  prep_w_body(W, Wt + which*36864, blockIdx.x * 256 + threadIdx.x);
}

__global__ __launch_bounds__(256) void prep_w(
    const float* __restrict__ W, u16* __restrict__ Wt)
{
  prep_w_body(W, Wt, blockIdx.x * 256 + threadIdx.x);
}

// ---------------------------------------------------------------------------
// Implicit-GEMM 3x3 conv (R12 champion): register-batched x-staging,
// frag-linear B with depth-1 prefetch, coalesced LDS epilogue.
// MFMA core verified R2-R16.
// ---------------------------------------------------------------------------
template<bool IN_F32, bool OUT_PROJ>
__device__ __forceinline__ void conv_body(
    const void* __restrict__ xin, const u16* __restrict__ Wt,
    const float* __restrict__ bias, void* __restrict__ dst,
    int frame, u16* xT, int tid)
{
  const int p = tid, py = p >> 4, px = p & 15;
  const int pp = (py + 1)*18 + px + 1;
  const float* xf = (const float*)xin + (size_t)frame * 16384;
  const u16*   xb = (const u16*)  xin + (size_t)frame * 16384;

  // issue ALL input loads first (latency hides under zero-fill + barrier)
  float xvf[64];
  u16   xvu[64];
  if (IN_F32){
    #pragma unroll
    for (int c = 0; c < 64; ++c) xvf[c] = xf[c*256 + p];
  } else {
    #pragma unroll
    for (int c = 0; c < 64; ++c) xvu[c] = xb[c*256 + p];
  }

  // zero xT (covers pad border rows)
  for (int i = tid; i < 2592; i += 256)
    *(uint4*)((char*)xT + i*16) = make_uint4(0u, 0u, 0u, 0u);
  __syncthreads();

  // pack from registers -> swizzled ds_write_b128
  #pragma unroll
  for (int cb = 0; cb < 8; ++cb){
    u16x8 pk;
    #pragma unroll
    for (int j = 0; j < 8; ++j)
      pk[j] = IN_F32 ? f2h(xvf[cb*8 + j]) : xvu[cb*8 + j];
    unsigned off = (unsigned)(pp*128) + ((((unsigned)cb + (unsigned)pp) & 7u) << 4);
    *(u16x8*)((char*)xT + off) = pk;
  }
  __syncthreads();

  const int w = tid >> 6, lane = tid & 63, lr = lane & 15, lg = lane >> 4;
  const int pyb = w * 4;

  f32x4 acc[4][4];
  #pragma unroll
  for (int n = 0; n < 4; ++n){
    float b = bias[n*16 + lr];
    #pragma unroll
    for (int m = 0; m < 4; ++m){
      acc[m][n][0] = b; acc[m][n][1] = b; acc[m][n][2] = b; acc[m][n][3] = b;
    }
  }

  #define LOADB(s, B) do {                                                  \
    _Pragma("unroll")                                                       \
    for (int n_ = 0; n_ < 4; ++n_)                                          \
      B[n_] = *(const f16x8*)(Wt + ((((s)*4 + n_)*64) + lane)*8);           \
  } while(0)

  #define STEP(s, B) do {                                                   \
    int tap_ = (s) >> 1, kk_ = (s) & 1;                                     \
    int dy_ = tap_ / 3, dx_ = tap_ - dy_*3;                                 \
    f16x8 af_[4];                                                           \
    _Pragma("unroll")                                                       \
    for (int m_ = 0; m_ < 4; ++m_){                                         \
      int pp_ = (pyb + m_ + dy_)*18 + lr + dx_;                             \
      unsigned slot_ = ((unsigned)(kk_*4 + lg) + (unsigned)pp_) & 7u;       \
      af_[m_] = *(const f16x8*)((const char*)xT                             \
                 + (unsigned)(pp_*128) + (slot_ << 4));                     \
    }                                                                       \
    _Pragma("unroll")                                                       \
    for (int m_ = 0; m_ < 4; ++m_)                                          \
      _Pragma("unroll")                                                     \
      for (int n_ = 0; n_ < 4; ++n_)                                        \
        acc[m_][n_] = __builtin_amdgcn_mfma_f32_16x16x32_f16(               \
            af_[m_], B[n_], acc[m_][n_], 0, 0, 0);                          \
  } while(0)

  f16x8 Ba[4], Bb[4];
  LOADB(0, Ba);
  #pragma unroll 1
  for (int it = 0; it < 9; ++it){
    LOADB(it*2 + 1, Bb);
    STEP(it*2, Ba);
    if (it < 8) LOADB(it*2 + 2, Ba);
    STEP(it*2 + 1, Bb);
  }
  #undef LOADB
  #undef STEP

  // ---- coalesced epilogue (R10, verified): xT dead -> C-transpose tile ----
  __syncthreads();
  char* xTc = (char*)xT;
  if (OUT_PROJ){
    #pragma unroll
    for (int n = 0; n < 4; ++n){
      int co = n*16 + lr;
      #pragma unroll
      for (int m = 0; m < 4; ++m){
        int px0 = w*64 + m*16 + lg*4;
        int s = px0 >> 3;
        unsigned aw = (unsigned)(co*512) + (unsigned)((s ^ (co & 7)) << 4)
                      + (unsigned)((px0 & 7) * 2);
        u16x4 o4;
        #pragma unroll
        for (int r = 0; r < 4; ++r) o4[r] = f2h(acc[m][n][r]);
        *(u16x4*)(xTc + aw) = o4;
      }
    }
    __syncthreads();
    u16* d = (u16*)dst;
    const int b = frame >> 8, sq = frame & 255;
    #pragma unroll
    for (int i = 0; i < 8; ++i){
      int c = w*8 + i;
      int co = c*2 + (lane >> 5);
      int pxo = (lane & 31) * 8;
      unsigned ld = (unsigned)(co*512) + (unsigned)(((lane & 31) ^ (co & 7)) << 4);
      uint4 v = *(const uint4*)(xTc + ld);
      int h = co >> 3, dk = co & 7;
      u16* gp = d + ((size_t)((b*8 + h)*256 + sq))*2048 + dk*256 + pxo;
      *(uint4*)gp = v;
    }
  } else {
    float* dfr = (float*)dst + (size_t)frame * 16384;
    #pragma unroll
    for (int ph2 = 0; ph2 < 2; ++ph2){
      if ((w >> 1) == ph2){
        #pragma unroll
        for (int n = 0; n < 4; ++n){
          int co = n*16 + lr;
          #pragma unroll
          for (int m = 0; m < 4; ++m){
            int pxl = (w & 1)*64 + m*16 + lg*4;
            int s = pxl >> 2;
            unsigned aw = (unsigned)(co*512) + (unsigned)((s ^ (co & 7)) << 4);
            *(f32x4*)(xTc + aw) = acc[m][n];
          }
        }
      }
      __syncthreads();
      #pragma unroll
      for (int i = 0; i < 8; ++i){
        int c = w*8 + i;
        int co = c*2 + (lane >> 5);
        int pxl = (lane & 31) * 4;
        unsigned ld = (unsigned)(co*512) + (unsigned)(((lane & 31) ^ (co & 7)) << 4);
        f32x4 v = *(const f32x4*)(xTc + ld);
        *(f32x4*)(dfr + co*256 + ph2*128 + pxl) = v;
      }
      if (ph2 == 0) __syncthreads();
    }
  }
}

// merged q/k/v projection convs: grid 1536 (which = blockIdx.x>>9)
__global__ __launch_bounds__(256, 3) void conv3_mfma(
    const float* __restrict__ q, const float* __restrict__ k,
    const float* __restrict__ v, const u16* __restrict__ Wt3,
    const float* __restrict__ bq, const float* __restrict__ bk,
    const float* __restrict__ bv,
    u16* __restrict__ qh, u16* __restrict__ kh, u16* __restrict__ vh)
{
  __shared__ __align__(16) u16 xT[324 * 64];     // 41472 B -> 3 blocks/CU
  const int which = blockIdx.x >> 9;
  const int frame = blockIdx.x & 511;
  const float* x = (which == 0) ? q : (which == 1) ? k : v;
  const float* bias = (which == 0) ? bq : (which == 1) ? bk : bv;
  u16* dst = (which == 0) ? qh : (which == 1) ? kh : vh;
  conv_body<true, true>(x, Wt3 + which*36864, bias, dst, frame, xT, threadIdx.x);
}

__global__ __launch_bounds__(256, 3) void conv_out_mfma(
    const u16* __restrict__ xin, const u16* __restrict__ Wt,
    const float* __restrict__ bias, float* __restrict__ out)
{
  __shared__ __align__(16) u16 xT[324 * 64];
  conv_body<false, false>(xin, Wt, bias, out, blockIdx.x, xT, threadIdx.x);
}

// ---------------------------------------------------------------------------
// V transpose: vh [bh][s][2048] -> vt [bh][d][256]  (verified)
// ---------------------------------------------------------------------------
__global__ __launch_bounds__(256) void transpose_v(
    const u16* __restrict__ vh, u16* __restrict__ vt)
{
  __shared__ u16 tile[64][72];
  const int tid = threadIdx.x;
  const int dt = blockIdx.x, st = blockIdx.y, bh = blockIdx.z;
  {
    int r = tid >> 2, c4 = tid & 3;
    const u16* src = vh + ((size_t)(bh*256 + st*64 + r))*2048 + dt*64 + c4*16;
    uint4 v0 = *(const uint4*)src;
    uint4 v1 = *(const uint4*)(src + 8);
    *(uint4*)&tile[r][c4*16]     = v0;
    *(uint4*)&tile[r][c4*16 + 8] = v1;
  }
  __syncthreads();
  {
    int dr = tid >> 2, s4 = tid & 3;
    u16 tmp[16];
    #pragma unroll
    for (int i = 0; i < 16; ++i) tmp[i] = tile[s4*16 + i][dr];
    u16* dstp = vt + ((size_t)(bh*2048 + dt*64 + dr))*256 + st*64 + s4*16;
    *(uint4*)dstp       = *(uint4*)&tmp[0];
    *(uint4*)(dstp + 8) = *(uint4*)&tmp[8];
  }
}

// ---------------------------------------------------------------------------
// Attention v3 (champion, fp16)
// ---------------------------------------------------------------------------
__global__ __launch_bounds__(512, 2) void attn_kernel(
    const u16* __restrict__ qh, const u16* __restrict__ kh,
    const u16* __restrict__ vt, u16* __restrict__ obuf)
{
  const float SCALE = 0.022097086912079608f;   // 1/sqrt(2048)
  __shared__ __align__(16) u16 Qs[16*2048];
  __shared__ __align__(16) u16 Kb[2][16384];
  __shared__ __align__(16) u16 P[16*256];
  __shared__ float redA[8][16];
  __shared__ float redB[8][16];

  const int tid = threadIdx.x;
  const int w = tid >> 6, lane = tid & 63, lr = lane & 15, lg = lane >> 4;

  const int id = blockIdx.x;
  const int xcd = id & 7, j = id >> 3;
  const int bh = xcd + 8*(j & 1), qt = j >> 1;
  const int q0 = qt * 16, b = bh >> 3, h = bh & 7;

  const u16* Qg = qh + ((size_t)(bh*256 + q0))*2048;
  const u16* Kg = kh + (size_t)bh * 256 * 2048;
  const u16* Vg = vt + (size_t)bh * 2048 * 256;

  const int spK = (lane & 7) ^ ((lane >> 3) & 7);
  #define STAGE_K(c, buf)                                                   \
    _Pragma("unroll")                                                       \
    for (int r_ = 0; r_ < 4; ++r_)                                          \
      cp16_async(Kg + (size_t)(w*32 + r_*8 + (lane>>3))*2048 + (c)*64 + spK*8, \
                 (buf) + w*2048 + r_*512);

  #define STAGE_V(c, buf)                                                   \
    _Pragma("unroll")                                                       \
    for (int r_ = 0; r_ < 8; ++r_){                                         \
      int rl_ = w*16 + r_*2 + (lane>>5);                                    \
      int sp_ = (lane & 31) ^ (rl_ & 7);                                    \
      cp16_async(Vg + (size_t)((c)*128 + rl_)*256 + sp_*8,                  \
                 (buf) + w*4096 + r_*512);                                  \
    }

  #pragma unroll
  for (int r = 0; r < 8; ++r){
    int t = r*64 + lane;
    int row = w*2 + (t >> 8);
    int dp = t & 255;
    int sp = (dp & ~7) | ((dp & 7) ^ (row & 7));
    cp16_async(Qg + (size_t)row*2048 + sp*8, Qs + w*4096 + r*512);
  }
  STAGE_K(0, Kb[0]);
  __syncthreads();

  const f32x4 zero4 = {0.f, 0.f, 0.f, 0.f};
  f32x4 sacc[2] = {zero4, zero4};
  #pragma unroll 1
  for (int c = 0; c < 32; ++c){
    if (c < 31) STAGE_K(c+1, Kb[(c+1)&1]);
    const u16* kb = Kb[c&1];
    #pragma unroll
    for (int d2 = 0; d2 < 2; ++d2){
      unsigned aoff = (((unsigned)lr << 12) + (unsigned)(c*128 + d2*64 + lg*16))
                      ^ (unsigned)((lr & 7) << 4);
      f16x8 a = *(const f16x8*)((const char*)Qs + aoff);
      #pragma unroll
      for (int n = 0; n < 2; ++n){
        int row = w*32 + n*16 + lr;
        const u16* kp = kb + row*64 + (((d2*4 + lg) ^ (row & 7)) << 3);
        f16x8 bk = *(const f16x8*)kp;
        sacc[n] = __builtin_amdgcn_mfma_f32_16x16x32_f16(a, bk, sacc[n], 0,0,0);
      }
    }
    __syncthreads();
  }

  float mx[4];
  #pragma unroll
  for (int r = 0; r < 4; ++r){
    float vv = fmaxf(sacc[0][r], sacc[1][r]);
    #pragma unroll
    for (int off = 1; off < 16; off <<= 1) vv = fmaxf(vv, __shfl_xor(vv, off));
    mx[r] = vv;
  }
  if (lr == 0){
    #pragma unroll
    for (int r = 0; r < 4; ++r) redA[w][lg*4 + r] = mx[r];
  }
  __syncthreads();
  #pragma unroll
  for (int r = 0; r < 4; ++r){
    int row = lg*4 + r;
    float vv = redA[0][row];
    #pragma unroll
    for (int ww = 1; ww < 8; ++ww) vv = fmaxf(vv, redA[ww][row]);
    mx[r] = vv;
  }

  const int kbase = w * 32;
  float sm[4] = {0.f, 0.f, 0.f, 0.f};
  #pragma unroll
  for (int n = 0; n < 2; ++n)
    #pragma unroll
    for (int r = 0; r < 4; ++r){
      float pv = __expf((sacc[n][r] - mx[r]) * SCALE);
      sm[r] += pv;
      int row = lg*4 + r;
      int col = kbase + n*16 + lr;
      unsigned off = (((unsigned)row << 9) + ((unsigned)col << 1))
                     ^ (unsigned)((row & 7) << 4);
      *(u16*)((char*)P + off) = f2h(pv);
    }
  #pragma unroll
  for (int r = 0; r < 4; ++r){
    float vv = sm[r];
    #pragma unroll
    for (int off = 1; off < 16; off <<= 1) vv += __shfl_xor(vv, off);
    sm[r] = vv;
  }
  if (lr == 0){
    #pragma unroll
    for (int r = 0; r < 4; ++r) redB[w][lg*4 + r] = sm[r];
  }
  __syncthreads();
  float rs[4];
  #pragma unroll
  for (int r = 0; r < 4; ++r){
    int row = lg*4 + r;
    float s = redB[0][row];
    #pragma unroll
    for (int ww = 1; ww < 8; ++ww) s += redB[ww][row];
    rs[r] = 1.0f / s;
  }

  u16* Vb0 = Qs;
  u16* Vb1 = &Kb[0][0];
  STAGE_V(0, Vb0);
  __syncthreads();
  #pragma unroll 1
  for (int c = 0; c < 16; ++c){
    if (c < 15){
      u16* nbuf = ((c+1) & 1) ? Vb1 : Vb0;
      STAGE_V(c+1, nbuf);
    }
    const u16* vb = (c & 1) ? Vb1 : Vb0;
    f32x4 oacc = zero4;
    #pragma unroll
    for (int kt = 0; kt < 8; ++kt){
      unsigned poff = (((unsigned)lr << 9) + (unsigned)(kt*64 + lg*16))
                      ^ (unsigned)((lr & 7) << 4);
      f16x8 pa = *(const f16x8*)((const char*)P + poff);
      int row = w*16 + lr;
      const u16* vp = vb + row*256 + (((kt*4 + lg) ^ (row & 7)) << 3);
      f16x8 bv = *(const f16x8*)vp;
      oacc = __builtin_amdgcn_mfma_f32_16x16x32_f16(pa, bv, oacc, 0,0,0);
    }
    #pragma unroll
    for (int r = 0; r < 4; ++r){
      float o = oacc[r] * rs[r];
      int qrow = q0 + lg*4 + r;
      int d = c*128 + w*16 + lr;
      int frame = b*256 + qrow;
      int cdim = h*8 + (d >> 8);
      obuf[((size_t)(frame*64 + cdim))*256 + (d & 255)] = f2h(o);
    }
    __syncthreads();
  }
  #undef STAGE_K
  #undef STAGE_V
}

// ---------------------------------------------------------------------------
extern "C" void kernel_launch(void* const* d_in, const int* in_sizes, int n_in,
                              void* d_out, int out_size, void* d_ws, size_t ws_size,
                              hipStream_t stream)
{
  const float* q  = (const float*)d_in[0];
  const float* k  = (const float*)d_in[1];
  const float* v  = (const float*)d_in[2];
  const float* Wq = (const float*)d_in[3];
  const float* bq = (const float*)d_in[4];
  const float* Wk = (const float*)d_in[5];
  const float* bk = (const float*)d_in[6];
  const float* Wv = (const float*)d_in[7];
  const float* bv = (const float*)d_in[8];
  const float* Wo = (const float*)d_in[9];
  const float* bo = (const float*)d_in[10];
  float* out = (float*)d_out;

  // Workspace (64 MB): qh[0,16M) kh[16,32M) vh[32,48M) vt[48,64M)
  char* ws = (char*)d_ws;
  u16* qh = (u16*)(ws);
  u16* kh = (u16*)(ws + (size_t)16*1024*1024);
  u16* vh = (u16*)(ws + (size_t)32*1024*1024);
  u16* vt = (u16*)(ws + (size_t)48*1024*1024);
  u16* obuf = vh;          // attn output frames (vh dead after transpose_v)
  u16* Wt3  = vt;          // weight packs; dead before transpose_v clobbers
  u16* WtO  = qh;          // qh dead after attn

  prep_w3<<<dim3(144, 3), dim3(256), 0, stream>>>(Wq, Wk, Wv, Wt3);
  conv3_mfma<<<dim3(1536), dim3(256), 0, stream>>>(q, k, v, Wt3, bq, bk, bv,
                                                   qh, kh, vh);
  transpose_v<<<dim3(32, 4, 16), dim3(256), 0, stream>>>(vh, vt);
  attn_kernel<<<dim3(256), dim3(512), 0, stream>>>(qh, kh, vt, obuf);
  prep_w<<<dim3(144), dim3(256), 0, stream>>>(Wo, WtO);
  conv_out_mfma<<<dim3(512), dim3(256), 0, stream>>>(obuf, WtO, bo, out);
}

// Round 18
// 113.564 us; speedup vs baseline: 1.1692x; 1.0170x over previous
//
#include <hip/hip_runtime.h>
#include <hip/hip_bf16.h>
#include <hip/hip_fp16.h>

typedef unsigned short u16;
typedef _Float16 f16x8 __attribute__((ext_vector_type(8)));
typedef u16 u16x8 __attribute__((ext_vector_type(8)));
typedef u16 u16x4 __attribute__((ext_vector_type(4)));
typedef float f32x4 __attribute__((ext_vector_type(4)));

__device__ __forceinline__ u16 f2h(float f){
  __half h = __float2half(f);
  return *(u16*)&h;
}

// async 16B global -> LDS (dest = wave-uniform base + lane*16; src per-lane)
__device__ __forceinline__ void cp16_async(const u16* g, u16* l){
  __builtin_amdgcn_global_load_lds(
      (const __attribute__((address_space(1))) unsigned int*)g,
      (__attribute__((address_space(3))) unsigned int*)l,
      16, 0, 0);
}

// ---------------------------------------------------------------------------
// Weight prep (verified): W f32 [co][ci][3][3] ->
// Wt fp16 frag-linear  Wt[((s*4+n)*64 + lane)*8 + j],  s=tap*2+(ci/32)
// ---------------------------------------------------------------------------
__device__ __forceinline__ void prep_w_body(const float* W, u16* Wt, int i){
  if (i >= 36864) return;
  int co = i / 576, rem = i % 576, ci = rem / 9, tap = rem % 9;
  int n = co >> 4, lr = co & 15, kk = ci >> 5, lg = (ci >> 3) & 3, j = ci & 7;
  int s = tap*2 + kk;
  Wt[(((s*4 + n)*64) + lg*16 + lr)*8 + j] = f2h(W[i]);
}

// up to 4 weight packs in one dispatch; W3/Wt3 may be null when ny==3
__global__ __launch_bounds__(256) void prep_w4(
    const float* __restrict__ W0, const float* __restrict__ W1,
    const float* __restrict__ W2, const float* __restrict__ W3,
    u16* __restrict__ T0, u16* __restrict__ T1,
    u16* __restrict__ T2, u16* __restrict__ T3)
{
  int which = blockIdx.y;
  const float* W = (which == 0) ? W0 : (which == 1) ? W1 :
                   (which == 2) ? W2 : W3;
  u16* T = (which == 0) ? T0 : (which == 1) ? T1 :
           (which == 2) ? T2 : T3;
  prep_w_body(W, T, blockIdx.x * 256 + threadIdx.x);
}

__global__ __launch_bounds__(256) void prep_w(
    const float* __restrict__ W, u16* __restrict__ Wt)
{
  prep_w_body(W, Wt, blockIdx.x * 256 + threadIdx.x);
}

// ---------------------------------------------------------------------------
// Implicit-GEMM 3x3 conv (R12/R17 champion): register-batched x-staging,
// frag-linear B with depth-1 prefetch, coalesced LDS epilogue.
// MFMA core verified R2-R17.
// ---------------------------------------------------------------------------
template<bool IN_F32, bool OUT_PROJ>
__device__ __forceinline__ void conv_body(
    const void* __restrict__ xin, const u16* __restrict__ Wt,
    const float* __restrict__ bias, void* __restrict__ dst,
    int frame, u16* xT, int tid)
{
  const int p = tid, py = p >> 4, px = p & 15;
  const int pp = (py + 1)*18 + px + 1;
  const float* xf = (const float*)xin + (size_t)frame * 16384;
  const u16*   xb = (const u16*)  xin + (size_t)frame * 16384;

  float xvf[64];
  u16   xvu[64];
  if (IN_F32){
    #pragma unroll
    for (int c = 0; c < 64; ++c) xvf[c] = xf[c*256 + p];
  } else {
    #pragma unroll
    for (int c = 0; c < 64; ++c) xvu[c] = xb[c*256 + p];
  }

  for (int i = tid; i < 2592; i += 256)
    *(uint4*)((char*)xT + i*16) = make_uint4(0u, 0u, 0u, 0u);
  __syncthreads();

  #pragma unroll
  for (int cb = 0; cb < 8; ++cb){
    u16x8 pk;
    #pragma unroll
    for (int j = 0; j < 8; ++j)
      pk[j] = IN_F32 ? f2h(xvf[cb*8 + j]) : xvu[cb*8 + j];
    unsigned off = (unsigned)(pp*128) + ((((unsigned)cb + (unsigned)pp) & 7u) << 4);
    *(u16x8*)((char*)xT + off) = pk;
  }
  __syncthreads();

  const int w = tid >> 6, lane = tid & 63, lr = lane & 15, lg = lane >> 4;
  const int pyb = w * 4;

  f32x4 acc[4][4];
  #pragma unroll
  for (int n = 0; n < 4; ++n){
    float b = bias[n*16 + lr];
    #pragma unroll
    for (int m = 0; m < 4; ++m){
      acc[m][n][0] = b; acc[m][n][1] = b; acc[m][n][2] = b; acc[m][n][3] = b;
    }
  }

  #define LOADB(s, B) do {                                                  \
    _Pragma("unroll")                                                       \
    for (int n_ = 0; n_ < 4; ++n_)                                          \
      B[n_] = *(const f16x8*)(Wt + ((((s)*4 + n_)*64) + lane)*8);           \
  } while(0)

  #define STEP(s, B) do {                                                   \
    int tap_ = (s) >> 1, kk_ = (s) & 1;                                     \
    int dy_ = tap_ / 3, dx_ = tap_ - dy_*3;                                 \
    f16x8 af_[4];                                                           \
    _Pragma("unroll")                                                       \
    for (int m_ = 0; m_ < 4; ++m_){                                         \
      int pp_ = (pyb + m_ + dy_)*18 + lr + dx_;                             \
      unsigned slot_ = ((unsigned)(kk_*4 + lg) + (unsigned)pp_) & 7u;       \
      af_[m_] = *(const f16x8*)((const char*)xT                             \
                 + (unsigned)(pp_*128) + (slot_ << 4));                     \
    }                                                                       \
    _Pragma("unroll")                                                       \
    for (int m_ = 0; m_ < 4; ++m_)                                          \
      _Pragma("unroll")                                                     \
      for (int n_ = 0; n_ < 4; ++n_)                                        \
        acc[m_][n_] = __builtin_amdgcn_mfma_f32_16x16x32_f16(               \
            af_[m_], B[n_], acc[m_][n_], 0, 0, 0);                          \
  } while(0)

  f16x8 Ba[4], Bb[4];
  LOADB(0, Ba);
  #pragma unroll 1
  for (int it = 0; it < 9; ++it){
    LOADB(it*2 + 1, Bb);
    STEP(it*2, Ba);
    if (it < 8) LOADB(it*2 + 2, Ba);
    STEP(it*2 + 1, Bb);
  }
  #undef LOADB
  #undef STEP

  __syncthreads();
  char* xTc = (char*)xT;
  if (OUT_PROJ){
    #pragma unroll
    for (int n = 0; n < 4; ++n){
      int co = n*16 + lr;
      #pragma unroll
      for (int m = 0; m < 4; ++m){
        int px0 = w*64 + m*16 + lg*4;
        int s = px0 >> 3;
        unsigned aw = (unsigned)(co*512) + (unsigned)((s ^ (co & 7)) << 4)
                      + (unsigned)((px0 & 7) * 2);
        u16x4 o4;
        #pragma unroll
        for (int r = 0; r < 4; ++r) o4[r] = f2h(acc[m][n][r]);
        *(u16x4*)(xTc + aw) = o4;
      }
    }
    __syncthreads();
    u16* d = (u16*)dst;
    const int b = frame >> 8, sq = frame & 255;
    #pragma unroll
    for (int i = 0; i < 8; ++i){
      int c = w*8 + i;
      int co = c*2 + (lane >> 5);
      int pxo = (lane & 31) * 8;
      unsigned ld = (unsigned)(co*512) + (unsigned)(((lane & 31) ^ (co & 7)) << 4);
      uint4 v = *(const uint4*)(xTc + ld);
      int h = co >> 3, dk = co & 7;
      u16* gp = d + ((size_t)((b*8 + h)*256 + sq))*2048 + dk*256 + pxo;
      *(uint4*)gp = v;
    }
  } else {
    float* dfr = (float*)dst + (size_t)frame * 16384;
    #pragma unroll
    for (int ph2 = 0; ph2 < 2; ++ph2){
      if ((w >> 1) == ph2){
        #pragma unroll
        for (int n = 0; n < 4; ++n){
          int co = n*16 + lr;
          #pragma unroll
          for (int m = 0; m < 4; ++m){
            int pxl = (w & 1)*64 + m*16 + lg*4;
            int s = pxl >> 2;
            unsigned aw = (unsigned)(co*512) + (unsigned)((s ^ (co & 7)) << 4);
            *(f32x4*)(xTc + aw) = acc[m][n];
          }
        }
      }
      __syncthreads();
      #pragma unroll
      for (int i = 0; i < 8; ++i){
        int c = w*8 + i;
        int co = c*2 + (lane >> 5);
        int pxl = (lane & 31) * 4;
        unsigned ld = (unsigned)(co*512) + (unsigned)(((lane & 31) ^ (co & 7)) << 4);
        f32x4 v = *(const f32x4*)(xTc + ld);
        *(f32x4*)(dfr + co*256 + ph2*128 + pxl) = v;
      }
      if (ph2 == 0) __syncthreads();
    }
  }
}

// merged q/k/v projection convs: grid 1536 (which = blockIdx.x>>9)
__global__ __launch_bounds__(256, 3) void conv3_mfma(
    const float* __restrict__ q, const float* __restrict__ k,
    const float* __restrict__ v, const u16* __restrict__ Wt3,
    const float* __restrict__ bq, const float* __restrict__ bk,
    const float* __restrict__ bv,
    u16* __restrict__ qh, u16* __restrict__ kh, u16* __restrict__ vh)
{
  __shared__ __align__(16) u16 xT[324 * 64];     // 41472 B -> 3 blocks/CU
  const int which = blockIdx.x >> 9;
  const int frame = blockIdx.x & 511;
  const float* x = (which == 0) ? q : (which == 1) ? k : v;
  const float* bias = (which == 0) ? bq : (which == 1) ? bk : bv;
  u16* dst = (which == 0) ? qh : (which == 1) ? kh : vh;
  conv_body<true, true>(x, Wt3 + which*36864, bias, dst, frame, xT, threadIdx.x);
}

__global__ __launch_bounds__(256, 3) void conv_out_mfma(
    const u16* __restrict__ xin, const u16* __restrict__ Wt,
    const float* __restrict__ bias, float* __restrict__ out)
{
  __shared__ __align__(16) u16 xT[324 * 64];
  conv_body<false, false>(xin, Wt, bias, out, blockIdx.x, xT, threadIdx.x);
}

// ---------------------------------------------------------------------------
// V transpose: vh [bh][s][2048] -> vt [bh][d][256]  (verified)
// ---------------------------------------------------------------------------
__global__ __launch_bounds__(256) void transpose_v(
    const u16* __restrict__ vh, u16* __restrict__ vt)
{
  __shared__ u16 tile[64][72];
  const int tid = threadIdx.x;
  const int dt = blockIdx.x, st = blockIdx.y, bh = blockIdx.z;
  {
    int r = tid >> 2, c4 = tid & 3;
    const u16* src = vh + ((size_t)(bh*256 + st*64 + r))*2048 + dt*64 + c4*16;
    uint4 v0 = *(const uint4*)src;
    uint4 v1 = *(const uint4*)(src + 8);
    *(uint4*)&tile[r][c4*16]     = v0;
    *(uint4*)&tile[r][c4*16 + 8] = v1;
  }
  __syncthreads();
  {
    int dr = tid >> 2, s4 = tid & 3;
    u16 tmp[16];
    #pragma unroll
    for (int i = 0; i < 16; ++i) tmp[i] = tile[s4*16 + i][dr];
    u16* dstp = vt + ((size_t)(bh*2048 + dt*64 + dr))*256 + st*64 + s4*16;
    *(uint4*)dstp       = *(uint4*)&tmp[0];
    *(uint4*)(dstp + 8) = *(uint4*)&tmp[8];
  }
}

// ---------------------------------------------------------------------------
// Attention v3 (champion, fp16)
// ---------------------------------------------------------------------------
__global__ __launch_bounds__(512, 2) void attn_kernel(
    const u16* __restrict__ qh, const u16* __restrict__ kh,
    const u16* __restrict__ vt, u16* __restrict__ obuf)
{
  const float SCALE = 0.022097086912079608f;   // 1/sqrt(2048)
  __shared__ __align__(16) u16 Qs[16*2048];
  __shared__ __align__(16) u16 Kb[2][16384];
  __shared__ __align__(16) u16 P[16*256];
  __shared__ float redA[8][16];
  __shared__ float redB[8][16];

  const int tid = threadIdx.x;
  const int w = tid >> 6, lane = tid & 63, lr = lane & 15, lg = lane >> 4;

  const int id = blockIdx.x;
  const int xcd = id & 7, j = id >> 3;
  const int bh = xcd + 8*(j & 1), qt = j >> 1;
  const int q0 = qt * 16, b = bh >> 3, h = bh & 7;

  const u16* Qg = qh + ((size_t)(bh*256 + q0))*2048;
  const u16* Kg = kh + (size_t)bh * 256 * 2048;
  const u16* Vg = vt + (size_t)bh * 2048 * 256;

  const int spK = (lane & 7) ^ ((lane >> 3) & 7);
  #define STAGE_K(c, buf)                                                   \
    _Pragma("unroll")                                                       \
    for (int r_ = 0; r_ < 4; ++r_)                                          \
      cp16_async(Kg + (size_t)(w*32 + r_*8 + (lane>>3))*2048 + (c)*64 + spK*8, \
                 (buf) + w*2048 + r_*512);

  #define STAGE_V(c, buf)                                                   \
    _Pragma("unroll")                                                       \
    for (int r_ = 0; r_ < 8; ++r_){                                         \
      int rl_ = w*16 + r_*2 + (lane>>5);                                    \
      int sp_ = (lane & 31) ^ (rl_ & 7);                                    \
      cp16_async(Vg + (size_t)((c)*128 + rl_)*256 + sp_*8,                  \
                 (buf) + w*4096 + r_*512);                                  \
    }

  #pragma unroll
  for (int r = 0; r < 8; ++r){
    int t = r*64 + lane;
    int row = w*2 + (t >> 8);
    int dp = t & 255;
    int sp = (dp & ~7) | ((dp & 7) ^ (row & 7));
    cp16_async(Qg + (size_t)row*2048 + sp*8, Qs + w*4096 + r*512);
  }
  STAGE_K(0, Kb[0]);
  __syncthreads();

  const f32x4 zero4 = {0.f, 0.f, 0.f, 0.f};
  f32x4 sacc[2] = {zero4, zero4};
  #pragma unroll 1
  for (int c = 0; c < 32; ++c){
    if (c < 31) STAGE_K(c+1, Kb[(c+1)&1]);
    const u16* kb = Kb[c&1];
    #pragma unroll
    for (int d2 = 0; d2 < 2; ++d2){
      unsigned aoff = (((unsigned)lr << 12) + (unsigned)(c*128 + d2*64 + lg*16))
                      ^ (unsigned)((lr & 7) << 4);
      f16x8 a = *(const f16x8*)((const char*)Qs + aoff);
      #pragma unroll
      for (int n = 0; n < 2; ++n){
        int row = w*32 + n*16 + lr;
        const u16* kp = kb + row*64 + (((d2*4 + lg) ^ (row & 7)) << 3);
        f16x8 bk = *(const f16x8*)kp;
        sacc[n] = __builtin_amdgcn_mfma_f32_16x16x32_f16(a, bk, sacc[n], 0,0,0);
      }
    }
    __syncthreads();
  }

  float mx[4];
  #pragma unroll
  for (int r = 0; r < 4; ++r){
    float vv = fmaxf(sacc[0][r], sacc[1][r]);
    #pragma unroll
    for (int off = 1; off < 16; off <<= 1) vv = fmaxf(vv, __shfl_xor(vv, off));
    mx[r] = vv;
  }
  if (lr == 0){
    #pragma unroll
    for (int r = 0; r < 4; ++r) redA[w][lg*4 + r] = mx[r];
  }
  __syncthreads();
  #pragma unroll
  for (int r = 0; r < 4; ++r){
    int row = lg*4 + r;
    float vv = redA[0][row];
    #pragma unroll
    for (int ww = 1; ww < 8; ++ww) vv = fmaxf(vv, redA[ww][row]);
    mx[r] = vv;
  }

  const int kbase = w * 32;
  float sm[4] = {0.f, 0.f, 0.f, 0.f};
  #pragma unroll
  for (int n = 0; n < 2; ++n)
    #pragma unroll
    for (int r = 0; r < 4; ++r){
      float pv = __expf((sacc[n][r] - mx[r]) * SCALE);
      sm[r] += pv;
      int row = lg*4 + r;
      int col = kbase + n*16 + lr;
      unsigned off = (((unsigned)row << 9) + ((unsigned)col << 1))
                     ^ (unsigned)((row & 7) << 4);
      *(u16*)((char*)P + off) = f2h(pv);
    }
  #pragma unroll
  for (int r = 0; r < 4; ++r){
    float vv = sm[r];
    #pragma unroll
    for (int off = 1; off < 16; off <<= 1) vv += __shfl_xor(vv, off);
    sm[r] = vv;
  }
  if (lr == 0){
    #pragma unroll
    for (int r = 0; r < 4; ++r) redB[w][lg*4 + r] = sm[r];
  }
  __syncthreads();
  float rs[4];
  #pragma unroll
  for (int r = 0; r < 4; ++r){
    int row = lg*4 + r;
    float s = redB[0][row];
    #pragma unroll
    for (int ww = 1; ww < 8; ++ww) s += redB[ww][row];
    rs[r] = 1.0f / s;
  }

  u16* Vb0 = Qs;
  u16* Vb1 = &Kb[0][0];
  STAGE_V(0, Vb0);
  __syncthreads();
  #pragma unroll 1
  for (int c = 0; c < 16; ++c){
    if (c < 15){
      u16* nbuf = ((c+1) & 1) ? Vb1 : Vb0;
      STAGE_V(c+1, nbuf);
    }
    const u16* vb = (c & 1) ? Vb1 : Vb0;
    f32x4 oacc = zero4;
    #pragma unroll
    for (int kt = 0; kt < 8; ++kt){
      unsigned poff = (((unsigned)lr << 9) + (unsigned)(kt*64 + lg*16))
                      ^ (unsigned)((lr & 7) << 4);
      f16x8 pa = *(const f16x8*)((const char*)P + poff);
      int row = w*16 + lr;
      const u16* vp = vb + row*256 + (((kt*4 + lg) ^ (row & 7)) << 3);
      f16x8 bv = *(const f16x8*)vp;
      oacc = __builtin_amdgcn_mfma_f32_16x16x32_f16(pa, bv, oacc, 0,0,0);
    }
    #pragma unroll
    for (int r = 0; r < 4; ++r){
      float o = oacc[r] * rs[r];
      int qrow = q0 + lg*4 + r;
      int d = c*128 + w*16 + lr;
      int frame = b*256 + qrow;
      int cdim = h*8 + (d >> 8);
      obuf[((size_t)(frame*64 + cdim))*256 + (d & 255)] = f2h(o);
    }
    __syncthreads();
  }
  #undef STAGE_K
  #undef STAGE_V
}

// ---------------------------------------------------------------------------
extern "C" void kernel_launch(void* const* d_in, const int* in_sizes, int n_in,
                              void* d_out, int out_size, void* d_ws, size_t ws_size,
                              hipStream_t stream)
{
  const float* q  = (const float*)d_in[0];
  const float* k  = (const float*)d_in[1];
  const float* v  = (const float*)d_in[2];
  const float* Wq = (const float*)d_in[3];
  const float* bq = (const float*)d_in[4];
  const float* Wk = (const float*)d_in[5];
  const float* bk = (const float*)d_in[6];
  const float* Wv = (const float*)d_in[7];
  const float* bv = (const float*)d_in[8];
  const float* Wo = (const float*)d_in[9];
  const float* bo = (const float*)d_in[10];
  float* out = (float*)d_out;

  // Workspace base layout (64 MB): qh[0,16M) kh[16,32M) vh[32,48M) vt[48,64M)
  char* ws = (char*)d_ws;
  u16* qh = (u16*)(ws);
  u16* kh = (u16*)(ws + (size_t)16*1024*1024);
  u16* vh = (u16*)(ws + (size_t)32*1024*1024);
  u16* vt = (u16*)(ws + (size_t)48*1024*1024);
  u16* obuf = vh;          // attn output frames (vh dead after transpose_v)
  u16* Wt3  = vt;          // weight packs; dead before transpose_v clobbers

  const size_t BASE = (size_t)64*1024*1024;
  const size_t WT_BYTES = 73728 * 2;           // 147456 B per pack
  bool early_wo = (ws_size >= BASE + WT_BYTES);

  if (early_wo){
    // WtO parked above the 64MB layout: survives the whole pipeline,
    // removes the mid-pipeline prep_w launch.
    u16* WtO = (u16*)(ws + BASE);
    prep_w4<<<dim3(144, 4), dim3(256), 0, stream>>>(Wq, Wk, Wv, Wo,
                                                    Wt3, Wt3 + 36864,
                                                    Wt3 + 73728, WtO);
    conv3_mfma<<<dim3(1536), dim3(256), 0, stream>>>(q, k, v, Wt3, bq, bk, bv,
                                                     qh, kh, vh);
    transpose_v<<<dim3(32, 4, 16), dim3(256), 0, stream>>>(vh, vt);
    attn_kernel<<<dim3(256), dim3(512), 0, stream>>>(qh, kh, vt, obuf);
    conv_out_mfma<<<dim3(512), dim3(256), 0, stream>>>(obuf, WtO, bo, out);
  } else {
    // Fallback = R17 champion schedule verbatim (WtO in qh after attn).
    u16* WtO = qh;
    prep_w4<<<dim3(144, 3), dim3(256), 0, stream>>>(Wq, Wk, Wv, Wq,
                                                    Wt3, Wt3 + 36864,
                                                    Wt3 + 73728, Wt3);
    conv3_mfma<<<dim3(1536), dim3(256), 0, stream>>>(q, k, v, Wt3, bq, bk, bv,
                                                     qh, kh, vh);
    transpose_v<<<dim3(32, 4, 16), dim3(256), 0, stream>>>(vh, vt);
    attn_kernel<<<dim3(256), dim3(512), 0, stream>>>(qh, kh, vt, obuf);
    prep_w<<<dim3(144), dim3(256), 0, stream>>>(Wo, WtO);
    conv_out_mfma<<<dim3(512), dim3(256), 0, stream>>>(obuf, WtO, bo, out);
  }
}

// Round 23
// 112.551 us; speedup vs baseline: 1.1797x; 1.0090x over previous
//
#include <hip/hip_runtime.h>
#include <hip/hip_bf16.h>
#include <hip/hip_fp16.h>

typedef unsigned short u16;
typedef _Float16 f16x8 __attribute__((ext_vector_type(8)));
typedef u16 u16x8 __attribute__((ext_vector_type(8)));
typedef u16 u16x4 __attribute__((ext_vector_type(4)));
typedef float f32x4 __attribute__((ext_vector_type(4)));

__device__ __forceinline__ u16 f2h(float f){
  __half h = __float2half(f);
  return *(u16*)&h;
}

// async 16B global -> LDS (dest = wave-uniform base + lane*16; src per-lane)
__device__ __forceinline__ void cp16_async(const u16* g, u16* l){
  __builtin_amdgcn_global_load_lds(
      (const __attribute__((address_space(1))) unsigned int*)g,
      (__attribute__((address_space(3))) unsigned int*)l,
      16, 0, 0);
}

// ---------------------------------------------------------------------------
// Weight prep (verified): W f32 [co][ci][3][3] ->
// Wt fp16 frag-linear  Wt[((s*4+n)*64 + lane)*8 + j],  s=tap*2+(ci/32)
// ---------------------------------------------------------------------------
__device__ __forceinline__ void prep_w_body(const float* W, u16* Wt, int i){
  if (i >= 36864) return;
  int co = i / 576, rem = i % 576, ci = rem / 9, tap = rem % 9;
  int n = co >> 4, lr = co & 15, kk = ci >> 5, lg = (ci >> 3) & 3, j = ci & 7;
  int s = tap*2 + kk;
  Wt[(((s*4 + n)*64) + lg*16 + lr)*8 + j] = f2h(W[i]);
}

__global__ __launch_bounds__(256) void prep_w4(
    const float* __restrict__ W0, const float* __restrict__ W1,
    const float* __restrict__ W2, const float* __restrict__ W3,
    u16* __restrict__ T0, u16* __restrict__ T1,
    u16* __restrict__ T2, u16* __restrict__ T3)
{
  int which = blockIdx.y;
  const float* W = (which == 0) ? W0 : (which == 1) ? W1 :
                   (which == 2) ? W2 : W3;
  u16* T = (which == 0) ? T0 : (which == 1) ? T1 :
           (which == 2) ? T2 : T3;
  prep_w_body(W, T, blockIdx.x * 256 + threadIdx.x);
}

__global__ __launch_bounds__(256) void prep_w(
    const float* __restrict__ W, u16* __restrict__ Wt)
{
  prep_w_body(W, Wt, blockIdx.x * 256 + threadIdx.x);
}

// ---------------------------------------------------------------------------
// Implicit-GEMM 3x3 conv (R12/R17/R18 measured champion): register-batched
// x-staging, frag-linear B with depth-1 prefetch, coalesced LDS epilogue.
// MFMA core verified R2-R18.
// ---------------------------------------------------------------------------
template<bool IN_F32, bool OUT_PROJ>
__device__ __forceinline__ void conv_body(
    const void* __restrict__ xin, const u16* __restrict__ Wt,
    const float* __restrict__ bias, void* __restrict__ dst,
    int frame, u16* xT, int tid)
{
  const int p = tid, py = p >> 4, px = p & 15;
  const int pp = (py + 1)*18 + px + 1;
  const float* xf = (const float*)xin + (size_t)frame * 16384;
  const u16*   xb = (const u16*)  xin + (size_t)frame * 16384;

  float xvf[64];
  u16   xvu[64];
  if (IN_F32){
    #pragma unroll
    for (int c = 0; c < 64; ++c) xvf[c] = xf[c*256 + p];
  } else {
    #pragma unroll
    for (int c = 0; c < 64; ++c) xvu[c] = xb[c*256 + p];
  }

  for (int i = tid; i < 2592; i += 256)
    *(uint4*)((char*)xT + i*16) = make_uint4(0u, 0u, 0u, 0u);
  __syncthreads();

  #pragma unroll
  for (int cb = 0; cb < 8; ++cb){
    u16x8 pk;
    #pragma unroll
    for (int j = 0; j < 8; ++j)
      pk[j] = IN_F32 ? f2h(xvf[cb*8 + j]) : xvu[cb*8 + j];
    unsigned off = (unsigned)(pp*128) + ((((unsigned)cb + (unsigned)pp) & 7u) << 4);
    *(u16x8*)((char*)xT + off) = pk;
  }
  __syncthreads();

  const int w = tid >> 6, lane = tid & 63, lr = lane & 15, lg = lane >> 4;
  const int pyb = w * 4;

  f32x4 acc[4][4];
  #pragma unroll
  for (int n = 0; n < 4; ++n){
    float b = bias[n*16 + lr];
    #pragma unroll
    for (int m = 0; m < 4; ++m){
      acc[m][n][0] = b; acc[m][n][1] = b; acc[m][n][2] = b; acc[m][n][3] = b;
    }
  }

  #define LOADB(s, B) do {                                                  \
    _Pragma("unroll")                                                       \
    for (int n_ = 0; n_ < 4; ++n_)                                          \
      B[n_] = *(const f16x8*)(Wt + ((((s)*4 + n_)*64) + lane)*8);           \
  } while(0)

  #define STEP(s, B) do {                                                   \
    int tap_ = (s) >> 1, kk_ = (s) & 1;                                     \
    int dy_ = tap_ / 3, dx_ = tap_ - dy_*3;                                 \
    f16x8 af_[4];                                                           \
    _Pragma("unroll")                                                       \
    for (int m_ = 0; m_ < 4; ++m_){                                         \
      int pp_ = (pyb + m_ + dy_)*18 + lr + dx_;                             \
      unsigned slot_ = ((unsigned)(kk_*4 + lg) + (unsigned)pp_) & 7u;       \
      af_[m_] = *(const f16x8*)((const char*)xT                             \
                 + (unsigned)(pp_*128) + (slot_ << 4));                     \
    }                                                                       \
    _Pragma("unroll")                                                       \
    for (int m_ = 0; m_ < 4; ++m_)                                          \
      _Pragma("unroll")                                                     \
      for (int n_ = 0; n_ < 4; ++n_)                                        \
        acc[m_][n_] = __builtin_amdgcn_mfma_f32_16x16x32_f16(               \
            af_[m_], B[n_], acc[m_][n_], 0, 0, 0);                          \
  } while(0)

  f16x8 Ba[4], Bb[4];
  LOADB(0, Ba);
  #pragma unroll 1
  for (int it = 0; it < 9; ++it){
    LOADB(it*2 + 1, Bb);
    STEP(it*2, Ba);
    if (it < 8) LOADB(it*2 + 2, Ba);
    STEP(it*2 + 1, Bb);
  }
  #undef LOADB
  #undef STEP

  __syncthreads();
  char* xTc = (char*)xT;
  if (OUT_PROJ){
    #pragma unroll
    for (int n = 0; n < 4; ++n){
      int co = n*16 + lr;
      #pragma unroll
      for (int m = 0; m < 4; ++m){
        int px0 = w*64 + m*16 + lg*4;
        int s = px0 >> 3;
        unsigned aw = (unsigned)(co*512) + (unsigned)((s ^ (co & 7)) << 4)
                      + (unsigned)((px0 & 7) * 2);
        u16x4 o4;
        #pragma unroll
        for (int r = 0; r < 4; ++r) o4[r] = f2h(acc[m][n][r]);
        *(u16x4*)(xTc + aw) = o4;
      }
    }
    __syncthreads();
    u16* d = (u16*)dst;
    const int b = frame >> 8, sq = frame & 255;
    #pragma unroll
    for (int i = 0; i < 8; ++i){
      int c = w*8 + i;
      int co = c*2 + (lane >> 5);
      int pxo = (lane & 31) * 8;
      unsigned ld = (unsigned)(co*512) + (unsigned)(((lane & 31) ^ (co & 7)) << 4);
      uint4 v = *(const uint4*)(xTc + ld);
      int h = co >> 3, dk = co & 7;
      u16* gp = d + ((size_t)((b*8 + h)*256 + sq))*2048 + dk*256 + pxo;
      *(uint4*)gp = v;
    }
  } else {
    float* dfr = (float*)dst + (size_t)frame * 16384;
    #pragma unroll
    for (int ph2 = 0; ph2 < 2; ++ph2){
      if ((w >> 1) == ph2){
        #pragma unroll
        for (int n = 0; n < 4; ++n){
          int co = n*16 + lr;
          #pragma unroll
          for (int m = 0; m < 4; ++m){
            int pxl = (w & 1)*64 + m*16 + lg*4;
            int s = pxl >> 2;
            unsigned aw = (unsigned)(co*512) + (unsigned)((s ^ (co & 7)) << 4);
            *(f32x4*)(xTc + aw) = acc[m][n];
          }
        }
      }
      __syncthreads();
      #pragma unroll
      for (int i = 0; i < 8; ++i){
        int c = w*8 + i;
        int co = c*2 + (lane >> 5);
        int pxl = (lane & 31) * 4;
        unsigned ld = (unsigned)(co*512) + (unsigned)(((lane & 31) ^ (co & 7)) << 4);
        f32x4 v = *(const f32x4*)(xTc + ld);
        *(f32x4*)(dfr + co*256 + ph2*128 + pxl) = v;
      }
      if (ph2 == 0) __syncthreads();
    }
  }
}

// merged q/k/v projection convs: grid 1536 (which = blockIdx.x>>9)
__global__ __launch_bounds__(256, 3) void conv3_mfma(
    const float* __restrict__ q, const float* __restrict__ k,
    const float* __restrict__ v, const u16* __restrict__ Wt3,
    const float* __restrict__ bq, const float* __restrict__ bk,
    const float* __restrict__ bv,
    u16* __restrict__ qh, u16* __restrict__ kh, u16* __restrict__ vh)
{
  __shared__ __align__(16) u16 xT[324 * 64];     // 41472 B -> 3 blocks/CU
  const int which = blockIdx.x >> 9;
  const int frame = blockIdx.x & 511;
  const float* x = (which == 0) ? q : (which == 1) ? k : v;
  const float* bias = (which == 0) ? bq : (which == 1) ? bk : bv;
  u16* dst = (which == 0) ? qh : (which == 1) ? kh : vh;
  conv_body<true, true>(x, Wt3 + which*36864, bias, dst, frame, xT, threadIdx.x);
}

__global__ __launch_bounds__(256, 3) void conv_out_mfma(
    const u16* __restrict__ xin, const u16* __restrict__ Wt,
    const float* __restrict__ bias, float* __restrict__ out)
{
  __shared__ __align__(16) u16 xT[324 * 64];
  conv_body<false, false>(xin, Wt, bias, out, blockIdx.x, xT, threadIdx.x);
}

// ---------------------------------------------------------------------------
// V transpose: vh [bh][s][2048] -> vt [bh][d][256]  (verified)
// ---------------------------------------------------------------------------
__global__ __launch_bounds__(256) void transpose_v(
    const u16* __restrict__ vh, u16* __restrict__ vt)
{
  __shared__ u16 tile[64][72];
  const int tid = threadIdx.x;
  const int dt = blockIdx.x, st = blockIdx.y, bh = blockIdx.z;
  {
    int r = tid >> 2, c4 = tid & 3;
    const u16* src = vh + ((size_t)(bh*256 + st*64 + r))*2048 + dt*64 + c4*16;
    uint4 v0 = *(const uint4*)src;
    uint4 v1 = *(const uint4*)(src + 8);
    *(uint4*)&tile[r][c4*16]     = v0;
    *(uint4*)&tile[r][c4*16 + 8] = v1;
  }
  __syncthreads();
  {
    int dr = tid >> 2, s4 = tid & 3;
    u16 tmp[16];
    #pragma unroll
    for (int i = 0; i < 16; ++i) tmp[i] = tile[s4*16 + i][dr];
    u16* dstp = vt + ((size_t)(bh*2048 + dt*64 + dr))*256 + st*64 + s4*16;
    *(uint4*)dstp       = *(uint4*)&tmp[0];
    *(uint4*)(dstp + 8) = *(uint4*)&tmp[8];
  }
}

// ---------------------------------------------------------------------------
// Attention v3 (measured champion, fp16)
// ---------------------------------------------------------------------------
__global__ __launch_bounds__(512, 2) void attn_kernel(
    const u16* __restrict__ qh, const u16* __restrict__ kh,
    const u16* __restrict__ vt, u16* __restrict__ obuf)
{
  const float SCALE = 0.022097086912079608f;   // 1/sqrt(2048)
  __shared__ __align__(16) u16 Qs[16*2048];
  __shared__ __align__(16) u16 Kb[2][16384];
  __shared__ __align__(16) u16 P[16*256];
  __shared__ float redA[8][16];
  __shared__ float redB[8][16];

  const int tid = threadIdx.x;
  const int w = tid >> 6, lane = tid & 63, lr = lane & 15, lg = lane >> 4;

  const int id = blockIdx.x;
  const int xcd = id & 7, j = id >> 3;
  const int bh = xcd + 8*(j & 1), qt = j >> 1;
  const int q0 = qt * 16, b = bh >> 3, h = bh & 7;

  const u16* Qg = qh + ((size_t)(bh*256 + q0))*2048;
  const u16* Kg = kh + (size_t)bh * 256 * 2048;
  const u16* Vg = vt + (size_t)bh * 2048 * 256;

  const int spK = (lane & 7) ^ ((lane >> 3) & 7);
  #define STAGE_K(c, buf)                                                   \
    _Pragma("unroll")                                                       \
    for (int r_ = 0; r_ < 4; ++r_)                                          \
      cp16_async(Kg + (size_t)(w*32 + r_*8 + (lane>>3))*2048 + (c)*64 + spK*8, \
                 (buf) + w*2048 + r_*512);

  #define STAGE_V(c, buf)                                                   \
    _Pragma("unroll")                                                       \
    for (int r_ = 0; r_ < 8; ++r_){                                         \
      int rl_ = w*16 + r_*2 + (lane>>5);                                    \
      int sp_ = (lane & 31) ^ (rl_ & 7);                                    \
      cp16_async(Vg + (size_t)((c)*128 + rl_)*256 + sp_*8,                  \
                 (buf) + w*4096 + r_*512);                                  \
    }

  #pragma unroll
  for (int r = 0; r < 8; ++r){
    int t = r*64 + lane;
    int row = w*2 + (t >> 8);
    int dp = t & 255;
    int sp = (dp & ~7) | ((dp & 7) ^ (row & 7));
    cp16_async(Qg + (size_t)row*2048 + sp*8, Qs + w*4096 + r*512);
  }
  STAGE_K(0, Kb[0]);
  __syncthreads();

  const f32x4 zero4 = {0.f, 0.f, 0.f, 0.f};
  f32x4 sacc[2] = {zero4, zero4};
  #pragma unroll 1
  for (int c = 0; c < 32; ++c){
    if (c < 31) STAGE_K(c+1, Kb[(c+1)&1]);
    const u16* kb = Kb[c&1];
    #pragma unroll
    for (int d2 = 0; d2 < 2; ++d2){
      unsigned aoff = (((unsigned)lr << 12) + (unsigned)(c*128 + d2*64 + lg*16))
                      ^ (unsigned)((lr & 7) << 4);
      f16x8 a = *(const f16x8*)((const char*)Qs + aoff);
      #pragma unroll
      for (int n = 0; n < 2; ++n){
        int row = w*32 + n*16 + lr;
        const u16* kp = kb + row*64 + (((d2*4 + lg) ^ (row & 7)) << 3);
        f16x8 bk = *(const f16x8*)kp;
        sacc[n] = __builtin_amdgcn_mfma_f32_16x16x32_f16(a, bk, sacc[n], 0,0,0);
      }
    }
    __syncthreads();
  }

  float mx[4];
  #pragma unroll
  for (int r = 0; r < 4; ++r){
    float vv = fmaxf(sacc[0][r], sacc[1][r]);
    #pragma unroll
    for (int off = 1; off < 16; off <<= 1) vv = fmaxf(vv, __shfl_xor(vv, off));
    mx[r] = vv;
  }
  if (lr == 0){
    #pragma unroll
    for (int r = 0; r < 4; ++r) redA[w][lg*4 + r] = mx[r];
  }
  __syncthreads();
  #pragma unroll
  for (int r = 0; r < 4; ++r){
    int row = lg*4 + r;
    float vv = redA[0][row];
    #pragma unroll
    for (int ww = 1; ww < 8; ++ww) vv = fmaxf(vv, redA[ww][row]);
    mx[r] = vv;
  }

  const int kbase = w * 32;
  float sm[4] = {0.f, 0.f, 0.f, 0.f};
  #pragma unroll
  for (int n = 0; n < 2; ++n)
    #pragma unroll
    for (int r = 0; r < 4; ++r){
      float pv = __expf((sacc[n][r] - mx[r]) * SCALE);
      sm[r] += pv;
      int row = lg*4 + r;
      int col = kbase + n*16 + lr;
      unsigned off = (((unsigned)row << 9) + ((unsigned)col << 1))
                     ^ (unsigned)((row & 7) << 4);
      *(u16*)((char*)P + off) = f2h(pv);
    }
  #pragma unroll
  for (int r = 0; r < 4; ++r){
    float vv = sm[r];
    #pragma unroll
    for (int off = 1; off < 16; off <<= 1) vv += __shfl_xor(vv, off);
    sm[r] = vv;
  }
  if (lr == 0){
    #pragma unroll
    for (int r = 0; r < 4; ++r) redB[w][lg*4 + r] = sm[r];
  }
  __syncthreads();
  float rs[4];
  #pragma unroll
  for (int r = 0; r < 4; ++r){
    int row = lg*4 + r;
    float s = redB[0][row];
    #pragma unroll
    for (int ww = 1; ww < 8; ++ww) s += redB[ww][row];
    rs[r] = 1.0f / s;
  }

  u16* Vb0 = Qs;
  u16* Vb1 = &Kb[0][0];
  STAGE_V(0, Vb0);
  __syncthreads();
  #pragma unroll 1
  for (int c = 0; c < 16; ++c){
    if (c < 15){
      u16* nbuf = ((c+1) & 1) ? Vb1 : Vb0;
      STAGE_V(c+1, nbuf);
    }
    const u16* vb = (c & 1) ? Vb1 : Vb0;
    f32x4 oacc = zero4;
    #pragma unroll
    for (int kt = 0; kt < 8; ++kt){
      unsigned poff = (((unsigned)lr << 9) + (unsigned)(kt*64 + lg*16))
                      ^ (unsigned)((lr & 7) << 4);
      f16x8 pa = *(const f16x8*)((const char*)P + poff);
      int row = w*16 + lr;
      const u16* vp = vb + row*256 + (((kt*4 + lg) ^ (row & 7)) << 3);
      f16x8 bv = *(const f16x8*)vp;
      oacc = __builtin_amdgcn_mfma_f32_16x16x32_f16(pa, bv, oacc, 0,0,0);
    }
    #pragma unroll
    for (int r = 0; r < 4; ++r){
      float o = oacc[r] * rs[r];
      int qrow = q0 + lg*4 + r;
      int d = c*128 + w*16 + lr;
      int frame = b*256 + qrow;
      int cdim = h*8 + (d >> 8);
      obuf[((size_t)(frame*64 + cdim))*256 + (d & 255)] = f2h(o);
    }
    __syncthreads();
  }
  #undef STAGE_K
  #undef STAGE_V
}

// ---------------------------------------------------------------------------
extern "C" void kernel_launch(void* const* d_in, const int* in_sizes, int n_in,
                              void* d_out, int out_size, void* d_ws, size_t ws_size,
                              hipStream_t stream)
{
  const float* q  = (const float*)d_in[0];
  const float* k  = (const float*)d_in[1];
  const float* v  = (const float*)d_in[2];
  const float* Wq = (const float*)d_in[3];
  const float* bq = (const float*)d_in[4];
  const float* Wk = (const float*)d_in[5];
  const float* bk = (const float*)d_in[6];
  const float* Wv = (const float*)d_in[7];
  const float* bv = (const float*)d_in[8];
  const float* Wo = (const float*)d_in[9];
  const float* bo = (const float*)d_in[10];
  float* out = (float*)d_out;

  // Workspace base layout (64 MB): qh[0,16M) kh[16,32M) vh[32,48M) vt[48,64M)
  char* ws = (char*)d_ws;
  u16* qh = (u16*)(ws);
  u16* kh = (u16*)(ws + (size_t)16*1024*1024);
  u16* vh = (u16*)(ws + (size_t)32*1024*1024);
  u16* vt = (u16*)(ws + (size_t)48*1024*1024);
  u16* obuf = vh;
  u16* Wt3  = vt;

  const size_t BASE = (size_t)64*1024*1024;
  const size_t WT_BYTES = 73728 * 2;
  bool early_wo = (ws_size >= BASE + WT_BYTES);

  if (early_wo){
    u16* WtO = (u16*)(ws + BASE);
    prep_w4<<<dim3(144, 4), dim3(256), 0, stream>>>(Wq, Wk, Wv, Wo,
                                                    Wt3, Wt3 + 36864,
                                                    Wt3 + 73728, WtO);
    conv3_mfma<<<dim3(1536), dim3(256), 0, stream>>>(q, k, v, Wt3, bq, bk, bv,
                                                     qh, kh, vh);
    transpose_v<<<dim3(32, 4, 16), dim3(256), 0, stream>>>(vh, vt);
    attn_kernel<<<dim3(256), dim3(512), 0, stream>>>(qh, kh, vt, obuf);
    conv_out_mfma<<<dim3(512), dim3(256), 0, stream>>>(obuf, WtO, bo, out);
  } else {
    u16* WtO = qh;
    prep_w4<<<dim3(144, 3), dim3(256), 0, stream>>>(Wq, Wk, Wv, Wq,
                                                    Wt3, Wt3 + 36864,
                                                    Wt3 + 73728, Wt3);
    conv3_mfma<<<dim3(1536), dim3(256), 0, stream>>>(q, k, v, Wt3, bq, bk, bv,
                                                     qh, kh, vh);
    transpose_v<<<dim3(32, 4, 16), dim3(256), 0, stream>>>(vh, vt);
    attn_kernel<<<dim3(256), dim3(512), 0, stream>>>(qh, kh, vt, obuf);
    prep_w<<<dim3(144), dim3(256), 0, stream>>>(Wo, WtO);
    conv_out_mfma<<<dim3(512), dim3(256), 0, stream>>>(obuf, WtO, bo, out);
  }
}